// Round 1
// 655.802 us; speedup vs baseline: 1.0049x; 1.0049x over previous
//
#include <hip/hip_runtime.h>
#include <stdint.h>
#include <stddef.h>

#define TB    4096
#define NDIM  1024
#define NH    16
#define KPROJ 256
#define DH    64
#define NBH   64

typedef _Float16 f16;
typedef _Float16 f16x8 __attribute__((ext_vector_type(8)));
typedef float    f32x4 __attribute__((ext_vector_type(4)));

__device__ __forceinline__ void glds16(const f16* g, f16* l) {
  __builtin_amdgcn_global_load_lds((const __attribute__((address_space(1))) void*)g,
                                   (__attribute__((address_space(3))) void*)l, 16, 0, 0);
}

// ---------------------------------------------------------------------------
// fp32 -> fp16 elementwise (X)
// ---------------------------------------------------------------------------
__launch_bounds__(256)
__global__ void cvt_x(const float* __restrict__ in, f16* __restrict__ out) {
  size_t i = ((size_t)blockIdx.x * 256 + threadIdx.x) * 8;
  float4 v0 = *(const float4*)(in + i);
  float4 v1 = *(const float4*)(in + i + 4);
  union { f16 h[8]; uint4 u; } pk;
  pk.h[0] = (f16)v0.x; pk.h[1] = (f16)v0.y; pk.h[2] = (f16)v0.z; pk.h[3] = (f16)v0.w;
  pk.h[4] = (f16)v1.x; pk.h[5] = (f16)v1.y; pk.h[6] = (f16)v1.z; pk.h[7] = (f16)v1.w;
  *(uint4*)(out + i) = pk.u;
}

// ---------------------------------------------------------------------------
// fp32 [R][C] -> fp16 transposed [C][R]
// ---------------------------------------------------------------------------
__launch_bounds__(256)
__global__ void cvt_t(const float* __restrict__ in, f16* __restrict__ out, int R, int C) {
  __shared__ __align__(16) f16 s[64][72];
  const int tid = threadIdx.x;
  const int c0 = blockIdx.x * 64, r0 = blockIdx.y * 64;
#pragma unroll
  for (int it = 0; it < 4; ++it) {
    int chunk = it * 256 + tid;
    int r_l = chunk >> 4, c4 = (chunk & 15) * 4;
    float4 v = *(const float4*)(in + (size_t)(r0 + r_l) * C + c0 + c4);
    s[c4 + 0][r_l] = (f16)v.x; s[c4 + 1][r_l] = (f16)v.y;
    s[c4 + 2][r_l] = (f16)v.z; s[c4 + 3][r_l] = (f16)v.w;
  }
  __syncthreads();
#pragma unroll
  for (int it = 0; it < 2; ++it) {
    int chunk = it * 256 + tid;
    int c_l = chunk >> 3, rc = (chunk & 7) * 8;
    *(uint4*)(out + (size_t)(c0 + c_l) * R + r0 + rc) = *(const uint4*)&s[c_l][rc];
  }
}

// ---------------------------------------------------------------------------
// Stage 1: qkv = Xh @ Wt^T  (M=16384, N=3072, K=1024) fp16 MFMA, 128x128x32.
// Epilogue: einops split f = 48d+16r+h, store q/k/v TRANSPOSED [bh][d][t].
// ---------------------------------------------------------------------------
__launch_bounds__(256)
__global__ void k_qkv(const f16* __restrict__ Xh, const f16* __restrict__ Wt,
                      f16* __restrict__ qt, f16* __restrict__ kvt) {
  __shared__ __align__(16) f16 As[128 * 32];
  __shared__ __align__(16) f16 Bs[128 * 32];
  const int tid = threadIdx.x;
  const int w = tid >> 6, lane = tid & 63;
  const int quad = lane >> 4, l15 = lane & 15;
  const int bn0 = blockIdx.x * 128, bm0 = blockIdx.y * 128;
  const int wm = (w & 1) * 64, wn = (w >> 1) * 64;
  const int srow = lane >> 2, skc = lane & 3;

  f32x4 acc[4][4];
#pragma unroll
  for (int i = 0; i < 4; ++i)
#pragma unroll
    for (int j = 0; j < 4; ++j) acc[i][j] = (f32x4){0.f, 0.f, 0.f, 0.f};

  const f16* Ag0 = Xh + (size_t)(bm0 + w * 32 + srow) * NDIM + skc * 8;
  const f16* Bg0 = Wt + (size_t)(bn0 + w * 32 + srow) * NDIM + skc * 8;
  f16* Al0 = As + (w * 32) * 32;
  f16* Bl0 = Bs + (w * 32) * 32;

  for (int k0 = 0; k0 < NDIM; k0 += 32) {
    glds16(Ag0 + k0, Al0);
    glds16(Ag0 + (size_t)16 * NDIM + k0, Al0 + 16 * 32);
    glds16(Bg0 + k0, Bl0);
    glds16(Bg0 + (size_t)16 * NDIM + k0, Bl0 + 16 * 32);
    __syncthreads();
    f16x8 a[4], b[4];
#pragma unroll
    for (int i = 0; i < 4; ++i) a[i] = *(const f16x8*)(As + (wm + i * 16 + l15) * 32 + quad * 8);
#pragma unroll
    for (int j = 0; j < 4; ++j) b[j] = *(const f16x8*)(Bs + (wn + j * 16 + l15) * 32 + quad * 8);
#pragma unroll
    for (int i = 0; i < 4; ++i)
#pragma unroll
      for (int j = 0; j < 4; ++j)
        acc[i][j] = __builtin_amdgcn_mfma_f32_16x16x32_f16(a[i], b[j], acc[i][j], 0, 0, 0);
    __syncthreads();
  }

#pragma unroll
  for (int i = 0; i < 4; ++i) {
    int mrow = bm0 + wm + i * 16 + quad * 4;
    int bb = mrow >> 12, t = mrow & 4095;
#pragma unroll
    for (int j = 0; j < 4; ++j) {
      int f = bn0 + wn + j * 16 + l15;
      int d = f / 48;
      int rem = f - d * 48;
      int rr = rem >> 4, h = rem & 15;
      f16* base = (rr == 0) ? qt : kvt + (size_t)(rr - 1) * ((size_t)NBH * DH * TB);
      size_t off = ((size_t)((bb * NH + h) * DH + d)) * TB + t;
      union { f16 hh[4]; uint2 u; } pk;
#pragma unroll
      for (int r = 0; r < 4; ++r) pk.hh[r] = (f16)acc[i][j][r];
      *(uint2*)(base + off) = pk.u;
    }
  }
}

// ---------------------------------------------------------------------------
// Stage 2: kp/vp = Pt @ kvt^T per (bh, r): M=128(kappa), N=64(d), K=4096(t).
// rv==0 (k): store kp [bh][kappa][d]   (contiguous d for S B-frags)
// rv==1 (v): store vpT [bh][d][kappa]  (contiguous kappa for PV B-frags)
// ---------------------------------------------------------------------------
__launch_bounds__(256)
__global__ void k_proj(const f16* __restrict__ Pt, const f16* __restrict__ kvt,
                       f16* __restrict__ kpv) {
  __shared__ __align__(16) f16 As[128 * 32];
  __shared__ __align__(16) f16 Bs[64 * 32];
  const int tid = threadIdx.x;
  const int w = tid >> 6, lane = tid & 63;
  const int quad = lane >> 4, l15 = lane & 15;
  const int km0 = blockIdx.x * 128;
  const int bh = blockIdx.y, rv = blockIdx.z;
  const int srow = lane >> 2, skc = lane & 3;
  const f16* Bbase = kvt + (size_t)(rv * NBH + bh) * DH * TB;  // [d][t]

  f32x4 acc[2][4];
#pragma unroll
  for (int i = 0; i < 2; ++i)
#pragma unroll
    for (int j = 0; j < 4; ++j) acc[i][j] = (f32x4){0.f, 0.f, 0.f, 0.f};

  const f16* Ag0 = Pt + (size_t)(km0 + w * 32 + srow) * TB + skc * 8;
  const f16* Bg0 = Bbase + (size_t)(w * 16 + srow) * TB + skc * 8;
  f16* Al0 = As + (w * 32) * 32;
  f16* Bl0 = Bs + (w * 16) * 32;

  for (int k0 = 0; k0 < TB; k0 += 32) {
    glds16(Ag0 + k0, Al0);
    glds16(Ag0 + (size_t)16 * TB + k0, Al0 + 16 * 32);
    glds16(Bg0 + k0, Bl0);
    __syncthreads();
    f16x8 a[2], b[4];
#pragma unroll
    for (int i = 0; i < 2; ++i) a[i] = *(const f16x8*)(As + (w * 32 + i * 16 + l15) * 32 + quad * 8);
#pragma unroll
    for (int j = 0; j < 4; ++j) b[j] = *(const f16x8*)(Bs + (j * 16 + l15) * 32 + quad * 8);
#pragma unroll
    for (int i = 0; i < 2; ++i)
#pragma unroll
      for (int j = 0; j < 4; ++j)
        acc[i][j] = __builtin_amdgcn_mfma_f32_16x16x32_f16(a[i], b[j], acc[i][j], 0, 0, 0);
    __syncthreads();
  }

  if (rv == 0) {
#pragma unroll
    for (int i = 0; i < 2; ++i) {
      int kap0 = km0 + w * 32 + i * 16 + quad * 4;
#pragma unroll
      for (int j = 0; j < 4; ++j) {
        int d = j * 16 + l15;
#pragma unroll
        for (int r = 0; r < 4; ++r)
          kpv[((size_t)bh * KPROJ + kap0 + r) * DH + d] = (f16)acc[i][j][r];
      }
    }
  } else {
    f16* vpT = kpv + (size_t)NBH * KPROJ * DH;
#pragma unroll
    for (int i = 0; i < 2; ++i) {
      int kap0 = km0 + w * 32 + i * 16 + quad * 4;
#pragma unroll
      for (int j = 0; j < 4; ++j) {
        int d = j * 16 + l15;
        union { f16 hh[4]; uint2 u; } pk;
#pragma unroll
        for (int r = 0; r < 4; ++r) pk.hh[r] = (f16)acc[i][j][r];
        *(uint2*)&vpT[((size_t)bh * DH + d) * KPROJ + kap0] = pk.u;
      }
    }
  }
}

// ---------------------------------------------------------------------------
// Stage 3+4: fused MFMA attention. grid (T/64, 64 bh), 4 waves; wave owns 16
// q-rows. q tile staged [64 d][64 t] in LDS via global_load_lds (coalesced),
// aliasing Ps (barrier-separated lifetimes). S = q@kp^T (16 n-tiles), softmax
// in C-layout regs, P via LDS round-trip (wave-private, padded), PV = P@vp
// with vpT B-frags from global. Output staged through Ps[w] -> 16B stores.
// ---------------------------------------------------------------------------
__launch_bounds__(256, 4)
__global__ void k_attn(const f16* __restrict__ qt, const f16* __restrict__ kpv,
                       f16* __restrict__ aout) {
  __shared__ __align__(16) f16 Ps[4][16][264];  // 33 KB, row stride 528B
  f16* Qs = &Ps[0][0][0];                       // alias: [64 d][64 t] linear, 8 KB
  const int tid = threadIdx.x;
  const int w = tid >> 6, lane = tid & 63;
  const int quad = lane >> 4, l15 = lane & 15;
  const int bh = blockIdx.y;
  const int tb = blockIdx.x * 64;
  const int b = bh >> 4, h = bh & 15;

  // stage q tile: qt [bh][d][t] rows are contiguous along t -> glds16 coalesced
  {
    const f16* qg = qt + (size_t)bh * DH * TB + tb;
#pragma unroll
    for (int c = 0; c < 2; ++c) {
      int d0 = w * 16 + c * 8;
      glds16(qg + (size_t)(d0 + (lane >> 3)) * TB + (lane & 7) * 8, Qs + d0 * 64);
    }
  }
  __syncthreads();

  // q A-frags: A[m=l15 (t)][k=quad*8+j (d)], one-time scalar LDS reads
  f16x8 aq[2];
#pragma unroll
  for (int ks = 0; ks < 2; ++ks)
#pragma unroll
    for (int j = 0; j < 8; ++j)
      aq[ks][j] = Qs[(ks * 32 + quad * 8 + j) * 64 + w * 16 + l15];
  __syncthreads();  // Qs dead from here; Ps region may be written

  // S: 16 n-tiles of 16 kappa; B-frags straight from global (L2-resident)
  f32x4 sc[16];
  const f16* kpb = kpv + (size_t)bh * (KPROJ * DH);
#pragma unroll 4
  for (int nt = 0; nt < 16; ++nt) {
    f16x8 b0 = *(const f16x8*)(kpb + (size_t)(nt * 16 + l15) * DH + quad * 8);
    f16x8 b1 = *(const f16x8*)(kpb + (size_t)(nt * 16 + l15) * DH + 32 + quad * 8);
    f32x4 c = (f32x4){0.f, 0.f, 0.f, 0.f};
    c = __builtin_amdgcn_mfma_f32_16x16x32_f16(aq[0], b0, c, 0, 0, 0);
    c = __builtin_amdgcn_mfma_f32_16x16x32_f16(aq[1], b1, c, 0, 0, 0);
    sc[nt] = c;
  }

  // softmax over the 256 columns; rows live at (quad*4+r), cols nt*16+l15
  float mx[4] = {-1e30f, -1e30f, -1e30f, -1e30f};
#pragma unroll
  for (int nt = 0; nt < 16; ++nt)
#pragma unroll
    for (int r = 0; r < 4; ++r) {
      float s = sc[nt][r] * 0.125f;
      sc[nt][r] = s;
      mx[r] = fmaxf(mx[r], s);
    }
#pragma unroll
  for (int r = 0; r < 4; ++r)
#pragma unroll
    for (int off = 1; off < 16; off <<= 1) mx[r] = fmaxf(mx[r], __shfl_xor(mx[r], off));
  float sm[4] = {0.f, 0.f, 0.f, 0.f};
#pragma unroll
  for (int nt = 0; nt < 16; ++nt)
#pragma unroll
    for (int r = 0; r < 4; ++r) {
      float e = __expf(sc[nt][r] - mx[r]);
      sc[nt][r] = e;
      sm[r] += e;
    }
#pragma unroll
  for (int r = 0; r < 4; ++r)
#pragma unroll
    for (int off = 1; off < 16; off <<= 1) sm[r] += __shfl_xor(sm[r], off);

  // P -> LDS (pack lane pairs -> b32 writes, even l15 lanes only)
#pragma unroll
  for (int nt = 0; nt < 16; ++nt)
#pragma unroll
    for (int r = 0; r < 4; ++r) {
      f16 hh = (f16)sc[nt][r];
      uint32_t hb = (uint32_t)__builtin_bit_cast(uint16_t, hh);
      uint32_t nb = (uint32_t)__shfl_xor((int)hb, 1);
      if (!(lane & 1))
        *(uint32_t*)&Ps[w][quad * 4 + r][nt * 16 + l15] = (hb & 0xffffu) | (nb << 16);
    }

  // PV: M=16 t, N=64 d, K=256 kappa; A from Ps, B from vpT global
  f32x4 oc[4];
#pragma unroll
  for (int j = 0; j < 4; ++j) oc[j] = (f32x4){0.f, 0.f, 0.f, 0.f};
  const f16* vpb = kpv + (size_t)NBH * KPROJ * DH + (size_t)bh * (DH * KPROJ);
#pragma unroll 2
  for (int kk = 0; kk < 8; ++kk) {
    f16x8 pa = *(const f16x8*)&Ps[w][l15][kk * 32 + quad * 8];
#pragma unroll
    for (int nd = 0; nd < 4; ++nd) {
      f16x8 bv = *(const f16x8*)(vpb + (size_t)(nd * 16 + l15) * KPROJ + kk * 32 + quad * 8);
      oc[nd] = __builtin_amdgcn_mfma_f32_16x16x32_f16(pa, bv, oc[nd], 0, 0, 0);
    }
  }

  // epilogue: divide by row sum, stage 16x64 tile in Ps[w] (dead after PV via
  // the oc data dependency), then fully-coalesced 16B stores (8 lanes/128B row)
#pragma unroll
  for (int nd = 0; nd < 4; ++nd)
#pragma unroll
    for (int r = 0; r < 4; ++r)
      Ps[w][quad * 4 + r][nd * 16 + l15] = (f16)(oc[nd][r] / sm[r]);

  const int orow = lane >> 3, oc8 = (lane & 7) * 8;
  const size_t obase = ((size_t)b * TB + tb + w * 16) * NDIM + h * 64 + oc8;
#pragma unroll
  for (int g = 0; g < 2; ++g)
    *(f16x8*)(aout + obase + (size_t)(g * 8 + orow) * NDIM) =
        *(const f16x8*)&Ps[w][g * 8 + orow][oc8];
}

// ---------------------------------------------------------------------------
// Stage 5: Out = aout @ W0t^T  (M=16384, N=1024, K=1024) fp16 MFMA, fp32 out.
// ---------------------------------------------------------------------------
__launch_bounds__(256)
__global__ void k_out(const f16* __restrict__ A, const f16* __restrict__ Bt,
                      float* __restrict__ Out) {
  __shared__ __align__(16) f16 As[128 * 32];
  __shared__ __align__(16) f16 Bs[128 * 32];
  const int tid = threadIdx.x;
  const int w = tid >> 6, lane = tid & 63;
  const int quad = lane >> 4, l15 = lane & 15;
  const int bn0 = blockIdx.x * 128, bm0 = blockIdx.y * 128;
  const int wm = (w & 1) * 64, wn = (w >> 1) * 64;
  const int srow = lane >> 2, skc = lane & 3;

  f32x4 acc[4][4];
#pragma unroll
  for (int i = 0; i < 4; ++i)
#pragma unroll
    for (int j = 0; j < 4; ++j) acc[i][j] = (f32x4){0.f, 0.f, 0.f, 0.f};

  const f16* Ag0 = A + (size_t)(bm0 + w * 32 + srow) * NDIM + skc * 8;
  const f16* Bg0 = Bt + (size_t)(bn0 + w * 32 + srow) * NDIM + skc * 8;
  f16* Al0 = As + (w * 32) * 32;
  f16* Bl0 = Bs + (w * 32) * 32;

  for (int k0 = 0; k0 < NDIM; k0 += 32) {
    glds16(Ag0 + k0, Al0);
    glds16(Ag0 + (size_t)16 * NDIM + k0, Al0 + 16 * 32);
    glds16(Bg0 + k0, Bl0);
    glds16(Bg0 + (size_t)16 * NDIM + k0, Bl0 + 16 * 32);
    __syncthreads();
    f16x8 a[4], b[4];
#pragma unroll
    for (int i = 0; i < 4; ++i) a[i] = *(const f16x8*)(As + (wm + i * 16 + l15) * 32 + quad * 8);
#pragma unroll
    for (int j = 0; j < 4; ++j) b[j] = *(const f16x8*)(Bs + (wn + j * 16 + l15) * 32 + quad * 8);
#pragma unroll
    for (int i = 0; i < 4; ++i)
#pragma unroll
      for (int j = 0; j < 4; ++j)
        acc[i][j] = __builtin_amdgcn_mfma_f32_16x16x32_f16(a[i], b[j], acc[i][j], 0, 0, 0);
    __syncthreads();
  }

#pragma unroll
  for (int i = 0; i < 4; ++i) {
    int m = bm0 + wm + i * 16 + quad * 4;
#pragma unroll
    for (int j = 0; j < 4; ++j) {
      int n = bn0 + wn + j * 16 + l15;
#pragma unroll
      for (int r = 0; r < 4; ++r) Out[(size_t)(m + r) * NDIM + n] = acc[i][j][r];
    }
  }
}

// ---------------------------------------------------------------------------
extern "C" void kernel_launch(void* const* d_in, const int* in_sizes, int n_in,
                              void* d_out, int out_size, void* d_ws, size_t ws_size,
                              hipStream_t stream) {
  const float* X    = (const float*)d_in[0];  // [4,4096,1024]
  const float* P    = (const float*)d_in[1];  // [4096,256]
  const float* Wqkv = (const float*)d_in[2];  // [1024,3072]
  const float* W0   = (const float*)d_in[3];  // [1024,1024]
  float* Out = (float*)d_out;

  char* ws = (char*)d_ws;
  const size_t MB = 1ull << 20;
  f16* Xh   = (f16*)(ws);             // 32 MB (reused as aout after k_qkv)
  f16* aout = (f16*)(ws);
  f16* qt   = (f16*)(ws + 32 * MB);   // 32 MB  [bh][d][t]
  f16* kvt  = (f16*)(ws + 64 * MB);   // 64 MB  [r][bh][d][t]
  f16* kpv  = (f16*)(ws + 128 * MB);  // 4 MB   kp [bh][kap][d] + vpT [bh][d][kap]
  f16* Wqt  = (f16*)(ws + 132 * MB);  // 6 MB   [3072][1024]
  f16* W0t  = (f16*)(ws + 138 * MB);  // 2 MB   [1024][1024]
  f16* Ptb  = (f16*)(ws + 140 * MB);  // 2 MB   [256][4096]

  cvt_x<<<dim3(8192), 256, 0, stream>>>(X, Xh);
  cvt_t<<<dim3(48, 16), 256, 0, stream>>>(Wqkv, Wqt, 1024, 3072);
  cvt_t<<<dim3(16, 16), 256, 0, stream>>>(W0, W0t, 1024, 1024);
  cvt_t<<<dim3(4, 64), 256, 0, stream>>>(P, Ptb, 4096, 256);
  k_qkv<<<dim3(24, 128), 256, 0, stream>>>(Xh, Wqt, qt, kvt);
  k_proj<<<dim3(2, 64, 2), 256, 0, stream>>>(Ptb, kvt, kpv);
  k_attn<<<dim3(64, 64), 256, 0, stream>>>(qt, kpv, aout);
  k_out<<<dim3(8, 128), 256, 0, stream>>>(aout, W0t, Out);
}

// Round 5
// 542.762 us; speedup vs baseline: 1.2142x; 1.2083x over previous
//
#include <hip/hip_runtime.h>
#include <stdint.h>
#include <stddef.h>

#define TB    4096
#define NDIM  1024
#define NH    16
#define KPROJ 256
#define DH    64
#define NBH   64

typedef _Float16 f16;
typedef _Float16 f16x8 __attribute__((ext_vector_type(8)));
typedef float    f32x4 __attribute__((ext_vector_type(4)));

__device__ __forceinline__ void glds16(const f16* g, f16* l) {
  __builtin_amdgcn_global_load_lds((const __attribute__((address_space(1))) void*)g,
                                   (__attribute__((address_space(3))) void*)l, 16, 0, 0);
}

// ---------------------------------------------------------------------------
// fp32 -> fp16 elementwise (X)
// ---------------------------------------------------------------------------
__launch_bounds__(256)
__global__ void cvt_x(const float* __restrict__ in, f16* __restrict__ out) {
  size_t i = ((size_t)blockIdx.x * 256 + threadIdx.x) * 8;
  float4 v0 = *(const float4*)(in + i);
  float4 v1 = *(const float4*)(in + i + 4);
  union { f16 h[8]; uint4 u; } pk;
  pk.h[0] = (f16)v0.x; pk.h[1] = (f16)v0.y; pk.h[2] = (f16)v0.z; pk.h[3] = (f16)v0.w;
  pk.h[4] = (f16)v1.x; pk.h[5] = (f16)v1.y; pk.h[6] = (f16)v1.z; pk.h[7] = (f16)v1.w;
  *(uint4*)(out + i) = pk.u;
}

// ---------------------------------------------------------------------------
// fp32 [R][C] -> fp16 transposed [C][R]
// ---------------------------------------------------------------------------
__launch_bounds__(256)
__global__ void cvt_t(const float* __restrict__ in, f16* __restrict__ out, int R, int C) {
  __shared__ __align__(16) f16 s[64][72];
  const int tid = threadIdx.x;
  const int c0 = blockIdx.x * 64, r0 = blockIdx.y * 64;
#pragma unroll
  for (int it = 0; it < 4; ++it) {
    int chunk = it * 256 + tid;
    int r_l = chunk >> 4, c4 = (chunk & 15) * 4;
    float4 v = *(const float4*)(in + (size_t)(r0 + r_l) * C + c0 + c4);
    s[c4 + 0][r_l] = (f16)v.x; s[c4 + 1][r_l] = (f16)v.y;
    s[c4 + 2][r_l] = (f16)v.z; s[c4 + 3][r_l] = (f16)v.w;
  }
  __syncthreads();
#pragma unroll
  for (int it = 0; it < 2; ++it) {
    int chunk = it * 256 + tid;
    int c_l = chunk >> 3, rc = (chunk & 7) * 8;
    *(uint4*)(out + (size_t)(c0 + c_l) * R + r0 + rc) = *(const uint4*)&s[c_l][rc];
  }
}

// ---------------------------------------------------------------------------
// Stage 1: qkv = Xh @ Wt^T  (M=16384, N=3072, K=1024) fp16 MFMA, 128x128x32.
// Epilogue: einops split f = 48d+16r+h, store q/k/v TRANSPOSED [bh][d][t].
// ---------------------------------------------------------------------------
__launch_bounds__(256)
__global__ void k_qkv(const f16* __restrict__ Xh, const f16* __restrict__ Wt,
                      f16* __restrict__ qt, f16* __restrict__ kvt) {
  __shared__ __align__(16) f16 As[128 * 32];
  __shared__ __align__(16) f16 Bs[128 * 32];
  const int tid = threadIdx.x;
  const int w = tid >> 6, lane = tid & 63;
  const int quad = lane >> 4, l15 = lane & 15;
  const int bn0 = blockIdx.x * 128, bm0 = blockIdx.y * 128;
  const int wm = (w & 1) * 64, wn = (w >> 1) * 64;
  const int srow = lane >> 2, skc = lane & 3;

  f32x4 acc[4][4];
#pragma unroll
  for (int i = 0; i < 4; ++i)
#pragma unroll
    for (int j = 0; j < 4; ++j) acc[i][j] = (f32x4){0.f, 0.f, 0.f, 0.f};

  const f16* Ag0 = Xh + (size_t)(bm0 + w * 32 + srow) * NDIM + skc * 8;
  const f16* Bg0 = Wt + (size_t)(bn0 + w * 32 + srow) * NDIM + skc * 8;
  f16* Al0 = As + (w * 32) * 32;
  f16* Bl0 = Bs + (w * 32) * 32;

  for (int k0 = 0; k0 < NDIM; k0 += 32) {
    glds16(Ag0 + k0, Al0);
    glds16(Ag0 + (size_t)16 * NDIM + k0, Al0 + 16 * 32);
    glds16(Bg0 + k0, Bl0);
    glds16(Bg0 + (size_t)16 * NDIM + k0, Bl0 + 16 * 32);
    __syncthreads();
    f16x8 a[4], b[4];
#pragma unroll
    for (int i = 0; i < 4; ++i) a[i] = *(const f16x8*)(As + (wm + i * 16 + l15) * 32 + quad * 8);
#pragma unroll
    for (int j = 0; j < 4; ++j) b[j] = *(const f16x8*)(Bs + (wn + j * 16 + l15) * 32 + quad * 8);
#pragma unroll
    for (int i = 0; i < 4; ++i)
#pragma unroll
      for (int j = 0; j < 4; ++j)
        acc[i][j] = __builtin_amdgcn_mfma_f32_16x16x32_f16(a[i], b[j], acc[i][j], 0, 0, 0);
    __syncthreads();
  }

#pragma unroll
  for (int i = 0; i < 4; ++i) {
    int mrow = bm0 + wm + i * 16 + quad * 4;
    int bb = mrow >> 12, t = mrow & 4095;
#pragma unroll
    for (int j = 0; j < 4; ++j) {
      int f = bn0 + wn + j * 16 + l15;
      int d = f / 48;
      int rem = f - d * 48;
      int rr = rem >> 4, h = rem & 15;
      f16* base = (rr == 0) ? qt : kvt + (size_t)(rr - 1) * ((size_t)NBH * DH * TB);
      size_t off = ((size_t)((bb * NH + h) * DH + d)) * TB + t;
      union { f16 hh[4]; uint2 u; } pk;
#pragma unroll
      for (int r = 0; r < 4; ++r) pk.hh[r] = (f16)acc[i][j][r];
      *(uint2*)(base + off) = pk.u;
    }
  }
}

// ---------------------------------------------------------------------------
// Stage 2: kp/vp = Pt @ kvt^T per (bh, r): M=128(kappa), N=64(d), K=4096(t).
// rv==0 (k): store kp [bh][kappa][d]   (contiguous d for S B-frags)
// rv==1 (v): store vpT [bh][d][kappa]  (contiguous kappa for PV B-frags)
// ---------------------------------------------------------------------------
__launch_bounds__(256)
__global__ void k_proj(const f16* __restrict__ Pt, const f16* __restrict__ kvt,
                       f16* __restrict__ kpv) {
  __shared__ __align__(16) f16 As[128 * 32];
  __shared__ __align__(16) f16 Bs[64 * 32];
  const int tid = threadIdx.x;
  const int w = tid >> 6, lane = tid & 63;
  const int quad = lane >> 4, l15 = lane & 15;
  const int km0 = blockIdx.x * 128;
  const int bh = blockIdx.y, rv = blockIdx.z;
  const int srow = lane >> 2, skc = lane & 3;
  const f16* Bbase = kvt + (size_t)(rv * NBH + bh) * DH * TB;  // [d][t]

  f32x4 acc[2][4];
#pragma unroll
  for (int i = 0; i < 2; ++i)
#pragma unroll
    for (int j = 0; j < 4; ++j) acc[i][j] = (f32x4){0.f, 0.f, 0.f, 0.f};

  const f16* Ag0 = Pt + (size_t)(km0 + w * 32 + srow) * TB + skc * 8;
  const f16* Bg0 = Bbase + (size_t)(w * 16 + srow) * TB + skc * 8;
  f16* Al0 = As + (w * 32) * 32;
  f16* Bl0 = Bs + (w * 16) * 32;

  for (int k0 = 0; k0 < TB; k0 += 32) {
    glds16(Ag0 + k0, Al0);
    glds16(Ag0 + (size_t)16 * TB + k0, Al0 + 16 * 32);
    glds16(Bg0 + k0, Bl0);
    __syncthreads();
    f16x8 a[2], b[4];
#pragma unroll
    for (int i = 0; i < 2; ++i) a[i] = *(const f16x8*)(As + (w * 32 + i * 16 + l15) * 32 + quad * 8);
#pragma unroll
    for (int j = 0; j < 4; ++j) b[j] = *(const f16x8*)(Bs + (j * 16 + l15) * 32 + quad * 8);
#pragma unroll
    for (int i = 0; i < 2; ++i)
#pragma unroll
      for (int j = 0; j < 4; ++j)
        acc[i][j] = __builtin_amdgcn_mfma_f32_16x16x32_f16(a[i], b[j], acc[i][j], 0, 0, 0);
    __syncthreads();
  }

  if (rv == 0) {
#pragma unroll
    for (int i = 0; i < 2; ++i) {
      int kap0 = km0 + w * 32 + i * 16 + quad * 4;
#pragma unroll
      for (int j = 0; j < 4; ++j) {
        int d = j * 16 + l15;
#pragma unroll
        for (int r = 0; r < 4; ++r)
          kpv[((size_t)bh * KPROJ + kap0 + r) * DH + d] = (f16)acc[i][j][r];
      }
    }
  } else {
    f16* vpT = kpv + (size_t)NBH * KPROJ * DH;
#pragma unroll
    for (int i = 0; i < 2; ++i) {
      int kap0 = km0 + w * 32 + i * 16 + quad * 4;
#pragma unroll
      for (int j = 0; j < 4; ++j) {
        int d = j * 16 + l15;
        union { f16 hh[4]; uint2 u; } pk;
#pragma unroll
        for (int r = 0; r < 4; ++r) pk.hh[r] = (f16)acc[i][j][r];
        *(uint2*)&vpT[((size_t)bh * DH + d) * KPROJ + kap0] = pk.u;
      }
    }
  }
}

// ---------------------------------------------------------------------------
// Stage 3+4: fused MFMA attention. grid (T/64, 64 bh), 4 waves; wave owns 16
// q-rows. q tile staged [64 d][64 t] in LDS via global_load_lds (aliases Ps,
// barrier-separated lifetimes). S = q@kp^T, 16 n-tiles FULLY UNROLLED so
// sc[16] stays in VGPRs (partial unroll => runtime index => scratch: that
// was ~700MB of HBM write traffic). softmax in regs, P via LDS round-trip,
// PV = P@vp with vpT B-frags from global. Output staged via Ps -> 16B stores.
// No XCD swizzle this round (bisect); no min-waves bound (no VGPR cap).
// ---------------------------------------------------------------------------
__launch_bounds__(256)
__global__ void k_attn(const f16* __restrict__ qt, const f16* __restrict__ kpv,
                       f16* __restrict__ aout) {
  __shared__ __align__(16) f16 Ps[4][16][264];  // 33 KB, row stride 528B
  f16* Qs = &Ps[0][0][0];                       // alias: [64 d][64 t] linear, 8 KB
  const int tid = threadIdx.x;
  const int w = tid >> 6, lane = tid & 63;
  const int quad = lane >> 4, l15 = lane & 15;
  const int bh = blockIdx.y;
  const int tb = blockIdx.x * 64;
  const int b = bh >> 4, h = bh & 15;

  // stage q tile: qt [bh][d][t] rows are contiguous along t -> glds16 coalesced
  {
    const f16* qg = qt + (size_t)bh * DH * TB + tb;
#pragma unroll
    for (int c = 0; c < 2; ++c) {
      int d0 = w * 16 + c * 8;
      glds16(qg + (size_t)(d0 + (lane >> 3)) * TB + (lane & 7) * 8, Qs + d0 * 64);
    }
  }
  __syncthreads();

  // q A-frags: A[m=l15 (t)][k=quad*8+j (d)], one-time scalar LDS reads
  f16x8 aq[2];
#pragma unroll
  for (int ks = 0; ks < 2; ++ks)
#pragma unroll
    for (int j = 0; j < 8; ++j)
      aq[ks][j] = Qs[(ks * 32 + quad * 8 + j) * 64 + w * 16 + l15];
  __syncthreads();  // Qs dead from here; Ps region may be written

  // S: 16 n-tiles of 16 kappa; B-frags straight from global (L2-resident).
  // FULL unroll: every sc index must be compile-time (register residency).
  f32x4 sc[16];
  const f16* kpb = kpv + (size_t)bh * (KPROJ * DH);
#pragma unroll
  for (int nt = 0; nt < 16; ++nt) {
    f16x8 b0 = *(const f16x8*)(kpb + (size_t)(nt * 16 + l15) * DH + quad * 8);
    f16x8 b1 = *(const f16x8*)(kpb + (size_t)(nt * 16 + l15) * DH + 32 + quad * 8);
    f32x4 c = (f32x4){0.f, 0.f, 0.f, 0.f};
    c = __builtin_amdgcn_mfma_f32_16x16x32_f16(aq[0], b0, c, 0, 0, 0);
    c = __builtin_amdgcn_mfma_f32_16x16x32_f16(aq[1], b1, c, 0, 0, 0);
    sc[nt] = c;
  }

  // softmax over the 256 columns; rows live at (quad*4+r), cols nt*16+l15
  float mx[4] = {-1e30f, -1e30f, -1e30f, -1e30f};
#pragma unroll
  for (int nt = 0; nt < 16; ++nt)
#pragma unroll
    for (int r = 0; r < 4; ++r) {
      float s = sc[nt][r] * 0.125f;
      sc[nt][r] = s;
      mx[r] = fmaxf(mx[r], s);
    }
#pragma unroll
  for (int r = 0; r < 4; ++r)
#pragma unroll
    for (int off = 1; off < 16; off <<= 1) mx[r] = fmaxf(mx[r], __shfl_xor(mx[r], off));
  float sm[4] = {0.f, 0.f, 0.f, 0.f};
#pragma unroll
  for (int nt = 0; nt < 16; ++nt)
#pragma unroll
    for (int r = 0; r < 4; ++r) {
      float e = __expf(sc[nt][r] - mx[r]);
      sc[nt][r] = e;
      sm[r] += e;
    }
#pragma unroll
  for (int r = 0; r < 4; ++r)
#pragma unroll
    for (int off = 1; off < 16; off <<= 1) sm[r] += __shfl_xor(sm[r], off);

  // P -> LDS (pack lane pairs -> b32 writes, even l15 lanes only)
#pragma unroll
  for (int nt = 0; nt < 16; ++nt)
#pragma unroll
    for (int r = 0; r < 4; ++r) {
      f16 hh = (f16)sc[nt][r];
      uint32_t hb = (uint32_t)__builtin_bit_cast(uint16_t, hh);
      uint32_t nb = (uint32_t)__shfl_xor((int)hb, 1);
      if (!(lane & 1))
        *(uint32_t*)&Ps[w][quad * 4 + r][nt * 16 + l15] = (hb & 0xffffu) | (nb << 16);
    }

  // PV: M=16 t, N=64 d, K=256 kappa; A from Ps, B from vpT global
  f32x4 oc[4];
#pragma unroll
  for (int j = 0; j < 4; ++j) oc[j] = (f32x4){0.f, 0.f, 0.f, 0.f};
  const f16* vpb = kpv + (size_t)NBH * KPROJ * DH + (size_t)bh * (DH * KPROJ);
#pragma unroll
  for (int kk = 0; kk < 8; ++kk) {
    f16x8 pa = *(const f16x8*)&Ps[w][l15][kk * 32 + quad * 8];
#pragma unroll
    for (int nd = 0; nd < 4; ++nd) {
      f16x8 bv = *(const f16x8*)(vpb + (size_t)(nd * 16 + l15) * KPROJ + kk * 32 + quad * 8);
      oc[nd] = __builtin_amdgcn_mfma_f32_16x16x32_f16(pa, bv, oc[nd], 0, 0, 0);
    }
  }

  // epilogue: divide by row sum, stage 16x64 tile in Ps[w] (dead after PV via
  // the oc data dependency), then fully-coalesced 16B stores (8 lanes/128B row)
#pragma unroll
  for (int nd = 0; nd < 4; ++nd)
#pragma unroll
    for (int r = 0; r < 4; ++r)
      Ps[w][quad * 4 + r][nd * 16 + l15] = (f16)(oc[nd][r] / sm[r]);

  const int orow = lane >> 3, oc8 = (lane & 7) * 8;
  const size_t obase = ((size_t)b * TB + tb + w * 16) * NDIM + h * 64 + oc8;
#pragma unroll
  for (int g = 0; g < 2; ++g)
    *(f16x8*)(aout + obase + (size_t)(g * 8 + orow) * NDIM) =
        *(const f16x8*)&Ps[w][g * 8 + orow][oc8];
}

// ---------------------------------------------------------------------------
// Stage 5: Out = aout @ W0t^T  (M=16384, N=1024, K=1024) fp16 MFMA, fp32 out.
// ---------------------------------------------------------------------------
__launch_bounds__(256)
__global__ void k_out(const f16* __restrict__ A, const f16* __restrict__ Bt,
                      float* __restrict__ Out) {
  __shared__ __align__(16) f16 As[128 * 32];
  __shared__ __align__(16) f16 Bs[128 * 32];
  const int tid = threadIdx.x;
  const int w = tid >> 6, lane = tid & 63;
  const int quad = lane >> 4, l15 = lane & 15;
  const int bn0 = blockIdx.x * 128, bm0 = blockIdx.y * 128;
  const int wm = (w & 1) * 64, wn = (w >> 1) * 64;
  const int srow = lane >> 2, skc = lane & 3;

  f32x4 acc[4][4];
#pragma unroll
  for (int i = 0; i < 4; ++i)
#pragma unroll
    for (int j = 0; j < 4; ++j) acc[i][j] = (f32x4){0.f, 0.f, 0.f, 0.f};

  const f16* Ag0 = A + (size_t)(bm0 + w * 32 + srow) * NDIM + skc * 8;
  const f16* Bg0 = Bt + (size_t)(bn0 + w * 32 + srow) * NDIM + skc * 8;
  f16* Al0 = As + (w * 32) * 32;
  f16* Bl0 = Bs + (w * 32) * 32;

  for (int k0 = 0; k0 < NDIM; k0 += 32) {
    glds16(Ag0 + k0, Al0);
    glds16(Ag0 + (size_t)16 * NDIM + k0, Al0 + 16 * 32);
    glds16(Bg0 + k0, Bl0);
    glds16(Bg0 + (size_t)16 * NDIM + k0, Bl0 + 16 * 32);
    __syncthreads();
    f16x8 a[4], b[4];
#pragma unroll
    for (int i = 0; i < 4; ++i) a[i] = *(const f16x8*)(As + (wm + i * 16 + l15) * 32 + quad * 8);
#pragma unroll
    for (int j = 0; j < 4; ++j) b[j] = *(const f16x8*)(Bs + (wn + j * 16 + l15) * 32 + quad * 8);
#pragma unroll
    for (int i = 0; i < 4; ++i)
#pragma unroll
      for (int j = 0; j < 4; ++j)
        acc[i][j] = __builtin_amdgcn_mfma_f32_16x16x32_f16(a[i], b[j], acc[i][j], 0, 0, 0);
    __syncthreads();
  }

#pragma unroll
  for (int i = 0; i < 4; ++i) {
    int m = bm0 + wm + i * 16 + quad * 4;
#pragma unroll
    for (int j = 0; j < 4; ++j) {
      int n = bn0 + wn + j * 16 + l15;
#pragma unroll
      for (int r = 0; r < 4; ++r) Out[(size_t)(m + r) * NDIM + n] = acc[i][j][r];
    }
  }
}

// ---------------------------------------------------------------------------
extern "C" void kernel_launch(void* const* d_in, const int* in_sizes, int n_in,
                              void* d_out, int out_size, void* d_ws, size_t ws_size,
                              hipStream_t stream) {
  const float* X    = (const float*)d_in[0];  // [4,4096,1024]
  const float* P    = (const float*)d_in[1];  // [4096,256]
  const float* Wqkv = (const float*)d_in[2];  // [1024,3072]
  const float* W0   = (const float*)d_in[3];  // [1024,1024]
  float* Out = (float*)d_out;

  char* ws = (char*)d_ws;
  const size_t MB = 1ull << 20;
  f16* Xh   = (f16*)(ws);             // 32 MB (reused as aout after k_qkv)
  f16* aout = (f16*)(ws);
  f16* qt   = (f16*)(ws + 32 * MB);   // 32 MB  [bh][d][t]
  f16* kvt  = (f16*)(ws + 64 * MB);   // 64 MB  [r][bh][d][t]
  f16* kpv  = (f16*)(ws + 128 * MB);  // 4 MB   kp [bh][kap][d] + vpT [bh][d][kap]
  f16* Wqt  = (f16*)(ws + 132 * MB);  // 6 MB   [3072][1024]
  f16* W0t  = (f16*)(ws + 138 * MB);  // 2 MB   [1024][1024]
  f16* Ptb  = (f16*)(ws + 140 * MB);  // 2 MB   [256][4096]

  cvt_x<<<dim3(8192), 256, 0, stream>>>(X, Xh);
  cvt_t<<<dim3(48, 16), 256, 0, stream>>>(Wqkv, Wqt, 1024, 3072);
  cvt_t<<<dim3(16, 16), 256, 0, stream>>>(W0, W0t, 1024, 1024);
  cvt_t<<<dim3(4, 64), 256, 0, stream>>>(P, Ptb, 4096, 256);
  k_qkv<<<dim3(24, 128), 256, 0, stream>>>(Xh, Wqt, qt, kvt);
  k_proj<<<dim3(2, 64, 2), 256, 0, stream>>>(Ptb, kvt, kpv);
  k_attn<<<dim3(64, 64), 256, 0, stream>>>(qt, kpv, aout);
  k_out<<<dim3(8, 128), 256, 0, stream>>>(aout, W0t, Out);
}

// Round 6
// 463.767 us; speedup vs baseline: 1.4210x; 1.1703x over previous
//
#include <hip/hip_runtime.h>
#include <stdint.h>
#include <stddef.h>

#define TB    4096
#define NDIM  1024
#define NH    16
#define KPROJ 256
#define DH    64
#define NBH   64

typedef _Float16 f16;
typedef _Float16 f16x8 __attribute__((ext_vector_type(8)));
typedef float    f32x4 __attribute__((ext_vector_type(4)));

__device__ __forceinline__ void glds16(const f16* g, f16* l) {
  __builtin_amdgcn_global_load_lds((const __attribute__((address_space(1))) void*)g,
                                   (__attribute__((address_space(3))) void*)l, 16, 0, 0);
}

// ---------------------------------------------------------------------------
// fp32 -> fp16 elementwise (X)
// ---------------------------------------------------------------------------
__launch_bounds__(256)
__global__ void cvt_x(const float* __restrict__ in, f16* __restrict__ out) {
  size_t i = ((size_t)blockIdx.x * 256 + threadIdx.x) * 8;
  float4 v0 = *(const float4*)(in + i);
  float4 v1 = *(const float4*)(in + i + 4);
  union { f16 h[8]; uint4 u; } pk;
  pk.h[0] = (f16)v0.x; pk.h[1] = (f16)v0.y; pk.h[2] = (f16)v0.z; pk.h[3] = (f16)v0.w;
  pk.h[4] = (f16)v1.x; pk.h[5] = (f16)v1.y; pk.h[6] = (f16)v1.z; pk.h[7] = (f16)v1.w;
  *(uint4*)(out + i) = pk.u;
}

// ---------------------------------------------------------------------------
// fp32 [R][C] -> fp16 transposed [C][R]
// ---------------------------------------------------------------------------
__launch_bounds__(256)
__global__ void cvt_t(const float* __restrict__ in, f16* __restrict__ out, int R, int C) {
  __shared__ __align__(16) f16 s[64][72];
  const int tid = threadIdx.x;
  const int c0 = blockIdx.x * 64, r0 = blockIdx.y * 64;
#pragma unroll
  for (int it = 0; it < 4; ++it) {
    int chunk = it * 256 + tid;
    int r_l = chunk >> 4, c4 = (chunk & 15) * 4;
    float4 v = *(const float4*)(in + (size_t)(r0 + r_l) * C + c0 + c4);
    s[c4 + 0][r_l] = (f16)v.x; s[c4 + 1][r_l] = (f16)v.y;
    s[c4 + 2][r_l] = (f16)v.z; s[c4 + 3][r_l] = (f16)v.w;
  }
  __syncthreads();
#pragma unroll
  for (int it = 0; it < 2; ++it) {
    int chunk = it * 256 + tid;
    int c_l = chunk >> 3, rc = (chunk & 7) * 8;
    *(uint4*)(out + (size_t)(c0 + c_l) * R + r0 + rc) = *(const uint4*)&s[c_l][rc];
  }
}

// ---------------------------------------------------------------------------
// Stage 1: qkv = Xh @ Wt^T  (M=16384, N=3072, K=1024) fp16 MFMA, 128x128x32.
// Epilogue: einops split f = 48d+16r+h, store q/k/v TRANSPOSED [bh][d][t].
// ---------------------------------------------------------------------------
__launch_bounds__(256)
__global__ void k_qkv(const f16* __restrict__ Xh, const f16* __restrict__ Wt,
                      f16* __restrict__ qt, f16* __restrict__ kvt) {
  __shared__ __align__(16) f16 As[128 * 32];
  __shared__ __align__(16) f16 Bs[128 * 32];
  const int tid = threadIdx.x;
  const int w = tid >> 6, lane = tid & 63;
  const int quad = lane >> 4, l15 = lane & 15;
  const int bn0 = blockIdx.x * 128, bm0 = blockIdx.y * 128;
  const int wm = (w & 1) * 64, wn = (w >> 1) * 64;
  const int srow = lane >> 2, skc = lane & 3;

  f32x4 acc[4][4];
#pragma unroll
  for (int i = 0; i < 4; ++i)
#pragma unroll
    for (int j = 0; j < 4; ++j) acc[i][j] = (f32x4){0.f, 0.f, 0.f, 0.f};

  const f16* Ag0 = Xh + (size_t)(bm0 + w * 32 + srow) * NDIM + skc * 8;
  const f16* Bg0 = Wt + (size_t)(bn0 + w * 32 + srow) * NDIM + skc * 8;
  f16* Al0 = As + (w * 32) * 32;
  f16* Bl0 = Bs + (w * 32) * 32;

  for (int k0 = 0; k0 < NDIM; k0 += 32) {
    glds16(Ag0 + k0, Al0);
    glds16(Ag0 + (size_t)16 * NDIM + k0, Al0 + 16 * 32);
    glds16(Bg0 + k0, Bl0);
    glds16(Bg0 + (size_t)16 * NDIM + k0, Bl0 + 16 * 32);
    __syncthreads();
    f16x8 a[4], b[4];
#pragma unroll
    for (int i = 0; i < 4; ++i) a[i] = *(const f16x8*)(As + (wm + i * 16 + l15) * 32 + quad * 8);
#pragma unroll
    for (int j = 0; j < 4; ++j) b[j] = *(const f16x8*)(Bs + (wn + j * 16 + l15) * 32 + quad * 8);
#pragma unroll
    for (int i = 0; i < 4; ++i)
#pragma unroll
      for (int j = 0; j < 4; ++j)
        acc[i][j] = __builtin_amdgcn_mfma_f32_16x16x32_f16(a[i], b[j], acc[i][j], 0, 0, 0);
    __syncthreads();
  }

#pragma unroll
  for (int i = 0; i < 4; ++i) {
    int mrow = bm0 + wm + i * 16 + quad * 4;
    int bb = mrow >> 12, t = mrow & 4095;
#pragma unroll
    for (int j = 0; j < 4; ++j) {
      int f = bn0 + wn + j * 16 + l15;
      int d = f / 48;
      int rem = f - d * 48;
      int rr = rem >> 4, h = rem & 15;
      f16* base = (rr == 0) ? qt : kvt + (size_t)(rr - 1) * ((size_t)NBH * DH * TB);
      size_t off = ((size_t)((bb * NH + h) * DH + d)) * TB + t;
      union { f16 hh[4]; uint2 u; } pk;
#pragma unroll
      for (int r = 0; r < 4; ++r) pk.hh[r] = (f16)acc[i][j][r];
      *(uint2*)(base + off) = pk.u;
    }
  }
}

// ---------------------------------------------------------------------------
// Stage 2: kp/vp = Pt @ kvt^T per (bh, r): M=128(kappa), N=64(d), K=4096(t).
// rv==0 (k): store kp [bh][kappa][d]   (contiguous d for S B-frags)
// rv==1 (v): store vpT [bh][d][kappa]  (contiguous kappa for PV B-frags)
// ---------------------------------------------------------------------------
__launch_bounds__(256)
__global__ void k_proj(const f16* __restrict__ Pt, const f16* __restrict__ kvt,
                       f16* __restrict__ kpv) {
  __shared__ __align__(16) f16 As[128 * 32];
  __shared__ __align__(16) f16 Bs[64 * 32];
  const int tid = threadIdx.x;
  const int w = tid >> 6, lane = tid & 63;
  const int quad = lane >> 4, l15 = lane & 15;
  const int km0 = blockIdx.x * 128;
  const int bh = blockIdx.y, rv = blockIdx.z;
  const int srow = lane >> 2, skc = lane & 3;
  const f16* Bbase = kvt + (size_t)(rv * NBH + bh) * DH * TB;  // [d][t]

  f32x4 acc[2][4];
#pragma unroll
  for (int i = 0; i < 2; ++i)
#pragma unroll
    for (int j = 0; j < 4; ++j) acc[i][j] = (f32x4){0.f, 0.f, 0.f, 0.f};

  const f16* Ag0 = Pt + (size_t)(km0 + w * 32 + srow) * TB + skc * 8;
  const f16* Bg0 = Bbase + (size_t)(w * 16 + srow) * TB + skc * 8;
  f16* Al0 = As + (w * 32) * 32;
  f16* Bl0 = Bs + (w * 16) * 32;

  for (int k0 = 0; k0 < TB; k0 += 32) {
    glds16(Ag0 + k0, Al0);
    glds16(Ag0 + (size_t)16 * TB + k0, Al0 + 16 * 32);
    glds16(Bg0 + k0, Bl0);
    __syncthreads();
    f16x8 a[2], b[4];
#pragma unroll
    for (int i = 0; i < 2; ++i) a[i] = *(const f16x8*)(As + (w * 32 + i * 16 + l15) * 32 + quad * 8);
#pragma unroll
    for (int j = 0; j < 4; ++j) b[j] = *(const f16x8*)(Bs + (j * 16 + l15) * 32 + quad * 8);
#pragma unroll
    for (int i = 0; i < 2; ++i)
#pragma unroll
      for (int j = 0; j < 4; ++j)
        acc[i][j] = __builtin_amdgcn_mfma_f32_16x16x32_f16(a[i], b[j], acc[i][j], 0, 0, 0);
    __syncthreads();
  }

  if (rv == 0) {
#pragma unroll
    for (int i = 0; i < 2; ++i) {
      int kap0 = km0 + w * 32 + i * 16 + quad * 4;
#pragma unroll
      for (int j = 0; j < 4; ++j) {
        int d = j * 16 + l15;
#pragma unroll
        for (int r = 0; r < 4; ++r)
          kpv[((size_t)bh * KPROJ + kap0 + r) * DH + d] = (f16)acc[i][j][r];
      }
    }
  } else {
    f16* vpT = kpv + (size_t)NBH * KPROJ * DH;
#pragma unroll
    for (int i = 0; i < 2; ++i) {
      int kap0 = km0 + w * 32 + i * 16 + quad * 4;
#pragma unroll
      for (int j = 0; j < 4; ++j) {
        int d = j * 16 + l15;
        union { f16 hh[4]; uint2 u; } pk;
#pragma unroll
        for (int r = 0; r < 4; ++r) pk.hh[r] = (f16)acc[i][j][r];
        *(uint2*)&vpT[((size_t)bh * DH + d) * KPROJ + kap0] = pk.u;
      }
    }
  }
}

// ---------------------------------------------------------------------------
// Stage 3+4: fused MFMA attention. grid (T/64, 64 bh), 4 waves; wave owns 16
// q-rows. NEW: kp (32KB) and vpT (32KB) staged through one shared LDS region
// (Ks) via async glds16 — kp at kernel start (with Qs), vpT issued right
// after the post-S barrier so its L3 latency hides under softmax+P-pack.
// Both use XOR swizzle col16 ^= (row&7), applied as linear LDS dest +
// inverse-swizzled GLOBAL source + swizzled ds_read (rule #21). This
// replaces 64 per-wave L2/L3-latency global loads with pipelined
// ds_read_b128, and cuts kpv requests 4x (shared across waves).
// S loop fully unrolled (sc[16] in VGPRs). LDS 66.5KB -> 2 blocks/CU.
// ---------------------------------------------------------------------------
__launch_bounds__(256)
__global__ void k_attn(const f16* __restrict__ qt, const f16* __restrict__ kpv,
                       f16* __restrict__ aout) {
  __shared__ __align__(16) f16 Ps[4][16][264];  // 33 KB; first 8KB doubles as Qs
  __shared__ __align__(16) f16 Ks[16384];       // 32 KB; kp, then vpT
  f16* Qs = &Ps[0][0][0];
  const int tid = threadIdx.x;
  const int w = tid >> 6, lane = tid & 63;
  const int quad = lane >> 4, l15 = lane & 15;
  const int bh = blockIdx.y;
  const int tb = blockIdx.x * 64;
  const int b = bh >> 4, h = bh & 15;

  const f16* kpb = kpv + (size_t)bh * (KPROJ * DH);
  const f16* vpb = kpv + (size_t)NBH * KPROJ * DH + (size_t)bh * (DH * KPROJ);

  // stage Qs [64d][64t] (linear) + kp [256][64] swizzled (col16 ^= row&7)
  {
    const f16* qg = qt + (size_t)bh * DH * TB + tb;
#pragma unroll
    for (int c = 0; c < 2; ++c) {
      int d0 = w * 16 + c * 8;
      glds16(qg + (size_t)(d0 + (lane >> 3)) * TB + (lane & 7) * 8, Qs + d0 * 64);
    }
    // lane l covers LDS slot row = w*64+it*8+(l>>3), col16 = l&7; global
    // source col16_g = (l&7)^(row&7) = (l&7)^(l>>3)  (w*64, it*8 are %8==0)
    const int kcolg = ((lane & 7) ^ (lane >> 3)) * 8;
    const int krow0 = w * 64 + (lane >> 3);
#pragma unroll
    for (int it = 0; it < 8; ++it)
      glds16(kpb + (size_t)(krow0 + it * 8) * DH + kcolg, Ks + w * 4096 + it * 512);
  }
  __syncthreads();

  // q A-frags: A[m=l15 (t)][k=quad*8+j (d)], one-time scalar LDS reads
  f16x8 aq[2];
#pragma unroll
  for (int ks = 0; ks < 2; ++ks)
#pragma unroll
    for (int j = 0; j < 8; ++j)
      aq[ks][j] = Qs[(ks * 32 + quad * 8 + j) * 64 + w * 16 + l15];

  // S: 16 n-tiles; B-frags from swizzled kp in LDS. Fully unrolled.
  f32x4 sc[16];
  const int sc0 = (quad ^ (l15 & 7)) * 8;  // swizzled f16 offset, b0
#pragma unroll
  for (int nt = 0; nt < 16; ++nt) {
    const f16* krow = Ks + (nt * 16 + l15) * 64;
    f16x8 b0 = *(const f16x8*)(krow + sc0);
    f16x8 b1 = *(const f16x8*)(krow + (sc0 ^ 32));  // col16^4 <=> f16off^32
    f32x4 c = (f32x4){0.f, 0.f, 0.f, 0.f};
    c = __builtin_amdgcn_mfma_f32_16x16x32_f16(aq[0], b0, c, 0, 0, 0);
    c = __builtin_amdgcn_mfma_f32_16x16x32_f16(aq[1], b1, c, 0, 0, 0);
    sc[nt] = c;
  }

  // softmax over the 256 columns; rows live at (quad*4+r), cols nt*16+l15
  float mx[4] = {-1e30f, -1e30f, -1e30f, -1e30f};
#pragma unroll
  for (int nt = 0; nt < 16; ++nt)
#pragma unroll
    for (int r = 0; r < 4; ++r) {
      float s = sc[nt][r] * 0.125f;
      sc[nt][r] = s;
      mx[r] = fmaxf(mx[r], s);
    }
#pragma unroll
  for (int r = 0; r < 4; ++r)
#pragma unroll
    for (int off = 1; off < 16; off <<= 1) mx[r] = fmaxf(mx[r], __shfl_xor(mx[r], off));

  // all waves done reading kp + Qs; region Ks may be restaged, Ps written
  __syncthreads();

  // issue vpT stage NOW (async); latency hides under exp/sum + P-pack below.
  // vpT [64][256] swizzled: slot row = w*16+it*2+(l>>5), col16 = l&31;
  // global col16_g = (l&31)^(row&7)
  {
#pragma unroll
    for (int it = 0; it < 8; ++it) {
      int r = w * 16 + it * 2 + (lane >> 5);
      int colg = ((lane & 31) ^ (r & 7)) * 8;
      glds16(vpb + (size_t)r * KPROJ + colg, Ks + w * 4096 + it * 512);
    }
  }

  float sm[4] = {0.f, 0.f, 0.f, 0.f};
#pragma unroll
  for (int nt = 0; nt < 16; ++nt)
#pragma unroll
    for (int r = 0; r < 4; ++r) {
      float e = __expf(sc[nt][r] - mx[r]);
      sc[nt][r] = e;
      sm[r] += e;
    }
#pragma unroll
  for (int r = 0; r < 4; ++r)
#pragma unroll
    for (int off = 1; off < 16; off <<= 1) sm[r] += __shfl_xor(sm[r], off);

  // P -> LDS (pack lane pairs -> b32 writes, even l15 lanes only)
#pragma unroll
  for (int nt = 0; nt < 16; ++nt)
#pragma unroll
    for (int r = 0; r < 4; ++r) {
      f16 hh = (f16)sc[nt][r];
      uint32_t hb = (uint32_t)__builtin_bit_cast(uint16_t, hh);
      uint32_t nb = (uint32_t)__shfl_xor((int)hb, 1);
      if (!(lane & 1))
        *(uint32_t*)&Ps[w][quad * 4 + r][nt * 16 + l15] = (hb & 0xffffu) | (nb << 16);
    }

  // vpT staged (vmcnt drained at barrier) + P visible
  __syncthreads();

  // PV: M=16 t, N=64 d, K=256 kappa; A from Ps[w], B from swizzled vpT in LDS
  f32x4 oc[4];
#pragma unroll
  for (int j = 0; j < 4; ++j) oc[j] = (f32x4){0.f, 0.f, 0.f, 0.f};
#pragma unroll
  for (int kk = 0; kk < 8; ++kk) {
    f16x8 pa = *(const f16x8*)&Ps[w][l15][kk * 32 + quad * 8];
#pragma unroll
    for (int nd = 0; nd < 4; ++nd) {
      int row = nd * 16 + l15;
      int c = ((kk * 4 + quad) ^ (l15 & 7)) * 8;  // swizzled col16
      f16x8 bv = *(const f16x8*)(Ks + row * KPROJ + c);
      oc[nd] = __builtin_amdgcn_mfma_f32_16x16x32_f16(pa, bv, oc[nd], 0, 0, 0);
    }
  }

  // epilogue: divide by row sum, stage 16x64 tile in Ps[w] (dead after PV via
  // the oc data dependency), then fully-coalesced 16B stores (8 lanes/128B row)
#pragma unroll
  for (int nd = 0; nd < 4; ++nd)
#pragma unroll
    for (int r = 0; r < 4; ++r)
      Ps[w][quad * 4 + r][nd * 16 + l15] = (f16)(oc[nd][r] / sm[r]);

  const int orow = lane >> 3, oc8 = (lane & 7) * 8;
  const size_t obase = ((size_t)b * TB + tb + w * 16) * NDIM + h * 64 + oc8;
#pragma unroll
  for (int g = 0; g < 2; ++g)
    *(f16x8*)(aout + obase + (size_t)(g * 8 + orow) * NDIM) =
        *(const f16x8*)&Ps[w][g * 8 + orow][oc8];
}

// ---------------------------------------------------------------------------
// Stage 5: Out = aout @ W0t^T  (M=16384, N=1024, K=1024) fp16 MFMA, fp32 out.
// ---------------------------------------------------------------------------
__launch_bounds__(256)
__global__ void k_out(const f16* __restrict__ A, const f16* __restrict__ Bt,
                      float* __restrict__ Out) {
  __shared__ __align__(16) f16 As[128 * 32];
  __shared__ __align__(16) f16 Bs[128 * 32];
  const int tid = threadIdx.x;
  const int w = tid >> 6, lane = tid & 63;
  const int quad = lane >> 4, l15 = lane & 15;
  const int bn0 = blockIdx.x * 128, bm0 = blockIdx.y * 128;
  const int wm = (w & 1) * 64, wn = (w >> 1) * 64;
  const int srow = lane >> 2, skc = lane & 3;

  f32x4 acc[4][4];
#pragma unroll
  for (int i = 0; i < 4; ++i)
#pragma unroll
    for (int j = 0; j < 4; ++j) acc[i][j] = (f32x4){0.f, 0.f, 0.f, 0.f};

  const f16* Ag0 = A + (size_t)(bm0 + w * 32 + srow) * NDIM + skc * 8;
  const f16* Bg0 = Bt + (size_t)(bn0 + w * 32 + srow) * NDIM + skc * 8;
  f16* Al0 = As + (w * 32) * 32;
  f16* Bl0 = Bs + (w * 32) * 32;

  for (int k0 = 0; k0 < NDIM; k0 += 32) {
    glds16(Ag0 + k0, Al0);
    glds16(Ag0 + (size_t)16 * NDIM + k0, Al0 + 16 * 32);
    glds16(Bg0 + k0, Bl0);
    glds16(Bg0 + (size_t)16 * NDIM + k0, Bl0 + 16 * 32);
    __syncthreads();
    f16x8 a[4], b[4];
#pragma unroll
    for (int i = 0; i < 4; ++i) a[i] = *(const f16x8*)(As + (wm + i * 16 + l15) * 32 + quad * 8);
#pragma unroll
    for (int j = 0; j < 4; ++j) b[j] = *(const f16x8*)(Bs + (wn + j * 16 + l15) * 32 + quad * 8);
#pragma unroll
    for (int i = 0; i < 4; ++i)
#pragma unroll
      for (int j = 0; j < 4; ++j)
        acc[i][j] = __builtin_amdgcn_mfma_f32_16x16x32_f16(a[i], b[j], acc[i][j], 0, 0, 0);
    __syncthreads();
  }

#pragma unroll
  for (int i = 0; i < 4; ++i) {
    int m = bm0 + wm + i * 16 + quad * 4;
#pragma unroll
    for (int j = 0; j < 4; ++j) {
      int n = bn0 + wn + j * 16 + l15;
#pragma unroll
      for (int r = 0; r < 4; ++r) Out[(size_t)(m + r) * NDIM + n] = acc[i][j][r];
    }
  }
}

// ---------------------------------------------------------------------------
extern "C" void kernel_launch(void* const* d_in, const int* in_sizes, int n_in,
                              void* d_out, int out_size, void* d_ws, size_t ws_size,
                              hipStream_t stream) {
  const float* X    = (const float*)d_in[0];  // [4,4096,1024]
  const float* P    = (const float*)d_in[1];  // [4096,256]
  const float* Wqkv = (const float*)d_in[2];  // [1024,3072]
  const float* W0   = (const float*)d_in[3];  // [1024,1024]
  float* Out = (float*)d_out;

  char* ws = (char*)d_ws;
  const size_t MB = 1ull << 20;
  f16* Xh   = (f16*)(ws);             // 32 MB (reused as aout after k_qkv)
  f16* aout = (f16*)(ws);
  f16* qt   = (f16*)(ws + 32 * MB);   // 32 MB  [bh][d][t]
  f16* kvt  = (f16*)(ws + 64 * MB);   // 64 MB  [r][bh][d][t]
  f16* kpv  = (f16*)(ws + 128 * MB);  // 4 MB   kp [bh][kap][d] + vpT [bh][d][kap]
  f16* Wqt  = (f16*)(ws + 132 * MB);  // 6 MB   [3072][1024]
  f16* W0t  = (f16*)(ws + 138 * MB);  // 2 MB   [1024][1024]
  f16* Ptb  = (f16*)(ws + 140 * MB);  // 2 MB   [256][4096]

  cvt_x<<<dim3(8192), 256, 0, stream>>>(X, Xh);
  cvt_t<<<dim3(48, 16), 256, 0, stream>>>(Wqkv, Wqt, 1024, 3072);
  cvt_t<<<dim3(16, 16), 256, 0, stream>>>(W0, W0t, 1024, 1024);
  cvt_t<<<dim3(4, 64), 256, 0, stream>>>(P, Ptb, 4096, 256);
  k_qkv<<<dim3(24, 128), 256, 0, stream>>>(Xh, Wqt, qt, kvt);
  k_proj<<<dim3(2, 64, 2), 256, 0, stream>>>(Ptb, kvt, kpv);
  k_attn<<<dim3(64, 64), 256, 0, stream>>>(qt, kpv, aout);
  k_out<<<dim3(8, 128), 256, 0, stream>>>(aout, W0t, Out);
}

// Round 7
// 448.573 us; speedup vs baseline: 1.4691x; 1.0339x over previous
//
#include <hip/hip_runtime.h>
#include <stdint.h>
#include <stddef.h>

#define TB    4096
#define NDIM  1024
#define NH    16
#define KPROJ 256
#define DH    64
#define NBH   64

typedef _Float16 f16;
typedef _Float16 f16x8 __attribute__((ext_vector_type(8)));
typedef float    f32x4 __attribute__((ext_vector_type(4)));

__device__ __forceinline__ void glds16(const f16* g, f16* l) {
  __builtin_amdgcn_global_load_lds((const __attribute__((address_space(1))) void*)g,
                                   (__attribute__((address_space(3))) void*)l, 16, 0, 0);
}

// ---------------------------------------------------------------------------
// fp32 -> fp16 elementwise (X)
// ---------------------------------------------------------------------------
__launch_bounds__(256)
__global__ void cvt_x(const float* __restrict__ in, f16* __restrict__ out) {
  size_t i = ((size_t)blockIdx.x * 256 + threadIdx.x) * 8;
  float4 v0 = *(const float4*)(in + i);
  float4 v1 = *(const float4*)(in + i + 4);
  union { f16 h[8]; uint4 u; } pk;
  pk.h[0] = (f16)v0.x; pk.h[1] = (f16)v0.y; pk.h[2] = (f16)v0.z; pk.h[3] = (f16)v0.w;
  pk.h[4] = (f16)v1.x; pk.h[5] = (f16)v1.y; pk.h[6] = (f16)v1.z; pk.h[7] = (f16)v1.w;
  *(uint4*)(out + i) = pk.u;
}

// ---------------------------------------------------------------------------
// fp32 [R][C] -> fp16 transposed [C][R]
// ---------------------------------------------------------------------------
__launch_bounds__(256)
__global__ void cvt_t(const float* __restrict__ in, f16* __restrict__ out, int R, int C) {
  __shared__ __align__(16) f16 s[64][72];
  const int tid = threadIdx.x;
  const int c0 = blockIdx.x * 64, r0 = blockIdx.y * 64;
#pragma unroll
  for (int it = 0; it < 4; ++it) {
    int chunk = it * 256 + tid;
    int r_l = chunk >> 4, c4 = (chunk & 15) * 4;
    float4 v = *(const float4*)(in + (size_t)(r0 + r_l) * C + c0 + c4);
    s[c4 + 0][r_l] = (f16)v.x; s[c4 + 1][r_l] = (f16)v.y;
    s[c4 + 2][r_l] = (f16)v.z; s[c4 + 3][r_l] = (f16)v.w;
  }
  __syncthreads();
#pragma unroll
  for (int it = 0; it < 2; ++it) {
    int chunk = it * 256 + tid;
    int c_l = chunk >> 3, rc = (chunk & 7) * 8;
    *(uint4*)(out + (size_t)(c0 + c_l) * R + r0 + rc) = *(const uint4*)&s[c_l][rc];
  }
}

// ---------------------------------------------------------------------------
// Stage 1: qkv = Xh @ Wt^T  (M=16384, N=3072, K=1024), 8-phase 256x256x64
// schedule (T2+T3+T4+T5). 512 thr / 8 waves; wave output = 256 rows x 32 cols
// (acc[16][2]); B-frags register-cached once per K-tile (phase 0), A frags
// phase-major (phase q = rows q*64..+64). LDS = 4 A-half-slots + 4 B-half-
// slots (128x64 f16 each, 128 KB total), both-sides XOR-16B swizzle
// (inverse-swizzled global src for glds16, swizzled ds_read). Half-tile
// stream order per tile: Bh0,Bh1,Ah0,Ah1; one half staged per phase, 3
// halves (vmcnt(6)) in flight across tile boundaries; vmcnt(0) only before
// the last tile. Raw s_barrier (no __syncthreads -> no vmcnt drain).
// Epilogue: einops split f = 48d+16r+h, store q/k/v TRANSPOSED [bh][d][t].
// ---------------------------------------------------------------------------
__launch_bounds__(512, 2)
__global__ void k_qkv(const f16* __restrict__ Xh, const f16* __restrict__ Wt,
                      f16* __restrict__ qt, f16* __restrict__ kvt) {
  __shared__ __align__(16) f16 sA[4][128 * 64];  // 64 KB, A half-slots
  __shared__ __align__(16) f16 sB[4][128 * 64];  // 64 KB, B half-slots
  const int tid = threadIdx.x;
  const int w = tid >> 6, lane = tid & 63;
  const int quad = lane >> 4, l15 = lane & 15;
  const int bn0 = blockIdx.x * 256, bm0 = blockIdx.y * 256;

  // staging geometry: per 64-row round, thread covers row w*8+(lane>>3),
  // 16B-group (lane&7); inverse swizzle on the GLOBAL column group.
  const int srow = w * 8 + (lane >> 3);
  const int scolg = ((lane & 7) ^ (lane >> 3)) * 8;
  const f16* Ag = Xh + (size_t)(bm0 + srow) * NDIM + scolg;
  const f16* Bg = Wt + (size_t)(bn0 + srow) * NDIM + scolg;

  auto stage = [&](int H) {  // H = global half index = 4*tile + {0:B0,1:B1,2:A0,3:A1}
    int h2 = H & 3, th = H >> 2;
    int k0 = th * 64;
    if (h2 < 2) {
      f16* slot = sB[(th & 1) * 2 + h2];
      const f16* g = Bg + (size_t)(h2 * 128) * NDIM + k0;
      glds16(g, slot + w * 512);
      glds16(g + (size_t)64 * NDIM, slot + 4096 + w * 512);
    } else {
      int h = h2 - 2;
      f16* slot = sA[(th & 1) * 2 + h];
      const f16* g = Ag + (size_t)(h * 128) * NDIM + k0;
      glds16(g, slot + w * 512);
      glds16(g + (size_t)64 * NDIM, slot + 4096 + w * 512);
    }
  };

  f32x4 acc[16][2];
#pragma unroll
  for (int i = 0; i < 16; ++i)
#pragma unroll
    for (int j = 0; j < 2; ++j) acc[i][j] = (f32x4){0.f, 0.f, 0.f, 0.f};

  // prologue: tile0 (4 halves) + tile1's B0,B1,A0 -> 7 halves, keep 3 in flight
  for (int H = 0; H < 7; ++H) stage(H);
  asm volatile("s_waitcnt vmcnt(6)" ::: "memory");
  __builtin_amdgcn_s_barrier();
  asm volatile("" ::: "memory");

  const int x0 = (quad ^ (l15 & 7)) * 8;  // swizzled f16 offset, ks=0
  const int x1 = x0 ^ 32;                 // ks=1: group^4 <=> f16off^32

  for (int t = 0; t < 16; ++t) {
    const f16* aS0 = sA[(t & 1) * 2];
    const f16* aS1 = sA[(t & 1) * 2 + 1];
    const f16* bS  = sB[(t & 1) * 2 + (w >> 2)];

    // B-frags for the whole K-tile (read once, kept in regs)
    f16x8 bf[2][2];
#pragma unroll
    for (int j = 0; j < 2; ++j) {
      const f16* r = bS + ((w & 3) * 32 + j * 16 + l15) * 64;
      bf[j][0] = *(const f16x8*)(r + x0);
      bf[j][1] = *(const f16x8*)(r + x1);
    }

#pragma unroll
    for (int q = 0; q < 4; ++q) {
      const f16* aS = (q >> 1) ? aS1 : aS0;
      f16x8 af[4][2];
#pragma unroll
      for (int i16 = 0; i16 < 4; ++i16) {
        const f16* r = aS + ((q & 1) * 64 + i16 * 16 + l15) * 64;
        af[i16][0] = *(const f16x8*)(r + x0);
        af[i16][1] = *(const f16x8*)(r + x1);
      }
      int H = 4 * t + q + 7;
      if (H < 64) stage(H);
      asm volatile("" ::: "memory");
      __builtin_amdgcn_s_barrier();
      __builtin_amdgcn_s_setprio(1);
#pragma unroll
      for (int i16 = 0; i16 < 4; ++i16)
#pragma unroll
        for (int j = 0; j < 2; ++j) {
          acc[q * 4 + i16][j] =
              __builtin_amdgcn_mfma_f32_16x16x32_f16(af[i16][0], bf[j][0], acc[q * 4 + i16][j], 0, 0, 0);
          acc[q * 4 + i16][j] =
              __builtin_amdgcn_mfma_f32_16x16x32_f16(af[i16][1], bf[j][1], acc[q * 4 + i16][j], 0, 0, 0);
        }
      __builtin_amdgcn_s_setprio(0);
      asm volatile("" ::: "memory");
      __builtin_amdgcn_s_barrier();
    }

    if (t < 15) {  // tile boundary: next tile fully resident; keep 3 halves in flight
      if (t == 14) asm volatile("s_waitcnt vmcnt(0)" ::: "memory");
      else         asm volatile("s_waitcnt vmcnt(6)" ::: "memory");
      __builtin_amdgcn_s_barrier();
      asm volatile("" ::: "memory");
    }
  }

  // epilogue: einops scatter, 8B stores (4 t-consecutive rows packed)
#pragma unroll
  for (int i = 0; i < 16; ++i) {
    int mrow = bm0 + i * 16 + quad * 4;
    int bb = mrow >> 12, tt = mrow & 4095;
#pragma unroll
    for (int j = 0; j < 2; ++j) {
      int f = bn0 + w * 32 + j * 16 + l15;
      int d = f / 48;
      int rem = f - d * 48;
      int rr = rem >> 4, h = rem & 15;
      f16* base = (rr == 0) ? qt : kvt + (size_t)(rr - 1) * ((size_t)NBH * DH * TB);
      size_t off = ((size_t)((bb * NH + h) * DH + d)) * TB + tt;
      union { f16 hh[4]; uint2 u; } pk;
#pragma unroll
      for (int r = 0; r < 4; ++r) pk.hh[r] = (f16)acc[i][j][r];
      *(uint2*)(base + off) = pk.u;
    }
  }
}

// ---------------------------------------------------------------------------
// Stage 2: kp/vp = Pt @ kvt^T per (bh, r): M=128(kappa), N=64(d), K=4096(t).
// rv==0 (k): store kp [bh][kappa][d]   (contiguous d for S B-frags)
// rv==1 (v): store vpT [bh][d][kappa]  (contiguous kappa for PV B-frags)
// ---------------------------------------------------------------------------
__launch_bounds__(256)
__global__ void k_proj(const f16* __restrict__ Pt, const f16* __restrict__ kvt,
                       f16* __restrict__ kpv) {
  __shared__ __align__(16) f16 As[128 * 32];
  __shared__ __align__(16) f16 Bs[64 * 32];
  const int tid = threadIdx.x;
  const int w = tid >> 6, lane = tid & 63;
  const int quad = lane >> 4, l15 = lane & 15;
  const int km0 = blockIdx.x * 128;
  const int bh = blockIdx.y, rv = blockIdx.z;
  const int srow = lane >> 2, skc = lane & 3;
  const f16* Bbase = kvt + (size_t)(rv * NBH + bh) * DH * TB;  // [d][t]

  f32x4 acc[2][4];
#pragma unroll
  for (int i = 0; i < 2; ++i)
#pragma unroll
    for (int j = 0; j < 4; ++j) acc[i][j] = (f32x4){0.f, 0.f, 0.f, 0.f};

  const f16* Ag0 = Pt + (size_t)(km0 + w * 32 + srow) * TB + skc * 8;
  const f16* Bg0 = Bbase + (size_t)(w * 16 + srow) * TB + skc * 8;
  f16* Al0 = As + (w * 32) * 32;
  f16* Bl0 = Bs + (w * 16) * 32;

  for (int k0 = 0; k0 < TB; k0 += 32) {
    glds16(Ag0 + k0, Al0);
    glds16(Ag0 + (size_t)16 * TB + k0, Al0 + 16 * 32);
    glds16(Bg0 + k0, Bl0);
    __syncthreads();
    f16x8 a[2], b[4];
#pragma unroll
    for (int i = 0; i < 2; ++i) a[i] = *(const f16x8*)(As + (w * 32 + i * 16 + l15) * 32 + quad * 8);
#pragma unroll
    for (int j = 0; j < 4; ++j) b[j] = *(const f16x8*)(Bs + (j * 16 + l15) * 32 + quad * 8);
#pragma unroll
    for (int i = 0; i < 2; ++i)
#pragma unroll
      for (int j = 0; j < 4; ++j)
        acc[i][j] = __builtin_amdgcn_mfma_f32_16x16x32_f16(a[i], b[j], acc[i][j], 0, 0, 0);
    __syncthreads();
  }

  if (rv == 0) {
#pragma unroll
    for (int i = 0; i < 2; ++i) {
      int kap0 = km0 + w * 32 + i * 16 + quad * 4;
#pragma unroll
      for (int j = 0; j < 4; ++j) {
        int d = j * 16 + l15;
#pragma unroll
        for (int r = 0; r < 4; ++r)
          kpv[((size_t)bh * KPROJ + kap0 + r) * DH + d] = (f16)acc[i][j][r];
      }
    }
  } else {
    f16* vpT = kpv + (size_t)NBH * KPROJ * DH;
#pragma unroll
    for (int i = 0; i < 2; ++i) {
      int kap0 = km0 + w * 32 + i * 16 + quad * 4;
#pragma unroll
      for (int j = 0; j < 4; ++j) {
        int d = j * 16 + l15;
        union { f16 hh[4]; uint2 u; } pk;
#pragma unroll
        for (int r = 0; r < 4; ++r) pk.hh[r] = (f16)acc[i][j][r];
        *(uint2*)&vpT[((size_t)bh * DH + d) * KPROJ + kap0] = pk.u;
      }
    }
  }
}

// ---------------------------------------------------------------------------
// Stage 3+4: fused MFMA attention (round-6 version, passing). kp/vpT staged
// through one shared 32KB LDS region via async glds16 with both-sides XOR
// swizzle; S fully unrolled (sc[16] in VGPRs); vpT stage latency hidden
// under softmax; output staged via Ps -> 16B coalesced stores.
// ---------------------------------------------------------------------------
__launch_bounds__(256)
__global__ void k_attn(const f16* __restrict__ qt, const f16* __restrict__ kpv,
                       f16* __restrict__ aout) {
  __shared__ __align__(16) f16 Ps[4][16][264];  // 33 KB; first 8KB doubles as Qs
  __shared__ __align__(16) f16 Ks[16384];       // 32 KB; kp, then vpT
  f16* Qs = &Ps[0][0][0];
  const int tid = threadIdx.x;
  const int w = tid >> 6, lane = tid & 63;
  const int quad = lane >> 4, l15 = lane & 15;
  const int bh = blockIdx.y;
  const int tb = blockIdx.x * 64;
  const int b = bh >> 4, h = bh & 15;

  const f16* kpb = kpv + (size_t)bh * (KPROJ * DH);
  const f16* vpb = kpv + (size_t)NBH * KPROJ * DH + (size_t)bh * (DH * KPROJ);

  // stage Qs [64d][64t] (linear) + kp [256][64] swizzled (col16 ^= row&7)
  {
    const f16* qg = qt + (size_t)bh * DH * TB + tb;
#pragma unroll
    for (int c = 0; c < 2; ++c) {
      int d0 = w * 16 + c * 8;
      glds16(qg + (size_t)(d0 + (lane >> 3)) * TB + (lane & 7) * 8, Qs + d0 * 64);
    }
    const int kcolg = ((lane & 7) ^ (lane >> 3)) * 8;
    const int krow0 = w * 64 + (lane >> 3);
#pragma unroll
    for (int it = 0; it < 8; ++it)
      glds16(kpb + (size_t)(krow0 + it * 8) * DH + kcolg, Ks + w * 4096 + it * 512);
  }
  __syncthreads();

  // q A-frags: A[m=l15 (t)][k=quad*8+j (d)], one-time scalar LDS reads
  f16x8 aq[2];
#pragma unroll
  for (int ks = 0; ks < 2; ++ks)
#pragma unroll
    for (int j = 0; j < 8; ++j)
      aq[ks][j] = Qs[(ks * 32 + quad * 8 + j) * 64 + w * 16 + l15];

  // S: 16 n-tiles; B-frags from swizzled kp in LDS. Fully unrolled.
  f32x4 sc[16];
  const int sc0 = (quad ^ (l15 & 7)) * 8;
#pragma unroll
  for (int nt = 0; nt < 16; ++nt) {
    const f16* krow = Ks + (nt * 16 + l15) * 64;
    f16x8 b0 = *(const f16x8*)(krow + sc0);
    f16x8 b1 = *(const f16x8*)(krow + (sc0 ^ 32));
    f32x4 c = (f32x4){0.f, 0.f, 0.f, 0.f};
    c = __builtin_amdgcn_mfma_f32_16x16x32_f16(aq[0], b0, c, 0, 0, 0);
    c = __builtin_amdgcn_mfma_f32_16x16x32_f16(aq[1], b1, c, 0, 0, 0);
    sc[nt] = c;
  }

  // softmax; rows live at (quad*4+r), cols nt*16+l15
  float mx[4] = {-1e30f, -1e30f, -1e30f, -1e30f};
#pragma unroll
  for (int nt = 0; nt < 16; ++nt)
#pragma unroll
    for (int r = 0; r < 4; ++r) {
      float s = sc[nt][r] * 0.125f;
      sc[nt][r] = s;
      mx[r] = fmaxf(mx[r], s);
    }
#pragma unroll
  for (int r = 0; r < 4; ++r)
#pragma unroll
    for (int off = 1; off < 16; off <<= 1) mx[r] = fmaxf(mx[r], __shfl_xor(mx[r], off));

  __syncthreads();  // all waves done reading kp + Qs

  // issue vpT stage NOW (async); latency hides under exp/sum + P-pack below
  {
#pragma unroll
    for (int it = 0; it < 8; ++it) {
      int r = w * 16 + it * 2 + (lane >> 5);
      int colg = ((lane & 31) ^ (r & 7)) * 8;
      glds16(vpb + (size_t)r * KPROJ + colg, Ks + w * 4096 + it * 512);
    }
  }

  float sm[4] = {0.f, 0.f, 0.f, 0.f};
#pragma unroll
  for (int nt = 0; nt < 16; ++nt)
#pragma unroll
    for (int r = 0; r < 4; ++r) {
      float e = __expf(sc[nt][r] - mx[r]);
      sc[nt][r] = e;
      sm[r] += e;
    }
#pragma unroll
  for (int r = 0; r < 4; ++r)
#pragma unroll
    for (int off = 1; off < 16; off <<= 1) sm[r] += __shfl_xor(sm[r], off);

  // P -> LDS (pack lane pairs -> b32 writes, even l15 lanes only)
#pragma unroll
  for (int nt = 0; nt < 16; ++nt)
#pragma unroll
    for (int r = 0; r < 4; ++r) {
      f16 hh = (f16)sc[nt][r];
      uint32_t hb = (uint32_t)__builtin_bit_cast(uint16_t, hh);
      uint32_t nb = (uint32_t)__shfl_xor((int)hb, 1);
      if (!(lane & 1))
        *(uint32_t*)&Ps[w][quad * 4 + r][nt * 16 + l15] = (hb & 0xffffu) | (nb << 16);
    }

  __syncthreads();  // vpT staged + P visible

  // PV: M=16 t, N=64 d, K=256 kappa; A from Ps[w], B from swizzled vpT in LDS
  f32x4 oc[4];
#pragma unroll
  for (int j = 0; j < 4; ++j) oc[j] = (f32x4){0.f, 0.f, 0.f, 0.f};
#pragma unroll
  for (int kk = 0; kk < 8; ++kk) {
    f16x8 pa = *(const f16x8*)&Ps[w][l15][kk * 32 + quad * 8];
#pragma unroll
    for (int nd = 0; nd < 4; ++nd) {
      int row = nd * 16 + l15;
      int c = ((kk * 4 + quad) ^ (l15 & 7)) * 8;
      f16x8 bv = *(const f16x8*)(Ks + row * KPROJ + c);
      oc[nd] = __builtin_amdgcn_mfma_f32_16x16x32_f16(pa, bv, oc[nd], 0, 0, 0);
    }
  }

  // epilogue: divide by row sum, stage tile in Ps[w], 16B coalesced stores
#pragma unroll
  for (int nd = 0; nd < 4; ++nd)
#pragma unroll
    for (int r = 0; r < 4; ++r)
      Ps[w][quad * 4 + r][nd * 16 + l15] = (f16)(oc[nd][r] / sm[r]);

  const int orow = lane >> 3, oc8 = (lane & 7) * 8;
  const size_t obase = ((size_t)b * TB + tb + w * 16) * NDIM + h * 64 + oc8;
#pragma unroll
  for (int g = 0; g < 2; ++g)
    *(f16x8*)(aout + obase + (size_t)(g * 8 + orow) * NDIM) =
        *(const f16x8*)&Ps[w][g * 8 + orow][oc8];
}

// ---------------------------------------------------------------------------
// Stage 5: Out = aout @ W0t^T  (M=16384, N=1024, K=1024) fp16 MFMA, fp32 out.
// ---------------------------------------------------------------------------
__launch_bounds__(256)
__global__ void k_out(const f16* __restrict__ A, const f16* __restrict__ Bt,
                      float* __restrict__ Out) {
  __shared__ __align__(16) f16 As[128 * 32];
  __shared__ __align__(16) f16 Bs[128 * 32];
  const int tid = threadIdx.x;
  const int w = tid >> 6, lane = tid & 63;
  const int quad = lane >> 4, l15 = lane & 15;
  const int bn0 = blockIdx.x * 128, bm0 = blockIdx.y * 128;
  const int wm = (w & 1) * 64, wn = (w >> 1) * 64;
  const int srow = lane >> 2, skc = lane & 3;

  f32x4 acc[4][4];
#pragma unroll
  for (int i = 0; i < 4; ++i)
#pragma unroll
    for (int j = 0; j < 4; ++j) acc[i][j] = (f32x4){0.f, 0.f, 0.f, 0.f};

  const f16* Ag0 = A + (size_t)(bm0 + w * 32 + srow) * NDIM + skc * 8;
  const f16* Bg0 = Bt + (size_t)(bn0 + w * 32 + srow) * NDIM + skc * 8;
  f16* Al0 = As + (w * 32) * 32;
  f16* Bl0 = Bs + (w * 32) * 32;

  for (int k0 = 0; k0 < NDIM; k0 += 32) {
    glds16(Ag0 + k0, Al0);
    glds16(Ag0 + (size_t)16 * NDIM + k0, Al0 + 16 * 32);
    glds16(Bg0 + k0, Bl0);
    glds16(Bg0 + (size_t)16 * NDIM + k0, Bl0 + 16 * 32);
    __syncthreads();
    f16x8 a[4], b[4];
#pragma unroll
    for (int i = 0; i < 4; ++i) a[i] = *(const f16x8*)(As + (wm + i * 16 + l15) * 32 + quad * 8);
#pragma unroll
    for (int j = 0; j < 4; ++j) b[j] = *(const f16x8*)(Bs + (wn + j * 16 + l15) * 32 + quad * 8);
#pragma unroll
    for (int i = 0; i < 4; ++i)
#pragma unroll
      for (int j = 0; j < 4; ++j)
        acc[i][j] = __builtin_amdgcn_mfma_f32_16x16x32_f16(a[i], b[j], acc[i][j], 0, 0, 0);
    __syncthreads();
  }

#pragma unroll
  for (int i = 0; i < 4; ++i) {
    int m = bm0 + wm + i * 16 + quad * 4;
#pragma unroll
    for (int j = 0; j < 4; ++j) {
      int n = bn0 + wn + j * 16 + l15;
#pragma unroll
      for (int r = 0; r < 4; ++r) Out[(size_t)(m + r) * NDIM + n] = acc[i][j][r];
    }
  }
}

// ---------------------------------------------------------------------------
extern "C" void kernel_launch(void* const* d_in, const int* in_sizes, int n_in,
                              void* d_out, int out_size, void* d_ws, size_t ws_size,
                              hipStream_t stream) {
  const float* X    = (const float*)d_in[0];  // [4,4096,1024]
  const float* P    = (const float*)d_in[1];  // [4096,256]
  const float* Wqkv = (const float*)d_in[2];  // [1024,3072]
  const float* W0   = (const float*)d_in[3];  // [1024,1024]
  float* Out = (float*)d_out;

  char* ws = (char*)d_ws;
  const size_t MB = 1ull << 20;
  f16* Xh   = (f16*)(ws);             // 32 MB (reused as aout after k_qkv)
  f16* aout = (f16*)(ws);
  f16* qt   = (f16*)(ws + 32 * MB);   // 32 MB  [bh][d][t]
  f16* kvt  = (f16*)(ws + 64 * MB);   // 64 MB  [r][bh][d][t]
  f16* kpv  = (f16*)(ws + 128 * MB);  // 4 MB   kp [bh][kap][d] + vpT [bh][d][kap]
  f16* Wqt  = (f16*)(ws + 132 * MB);  // 6 MB   [3072][1024]
  f16* W0t  = (f16*)(ws + 138 * MB);  // 2 MB   [1024][1024]
  f16* Ptb  = (f16*)(ws + 140 * MB);  // 2 MB   [256][4096]

  cvt_x<<<dim3(8192), 256, 0, stream>>>(X, Xh);
  cvt_t<<<dim3(48, 16), 256, 0, stream>>>(Wqkv, Wqt, 1024, 3072);
  cvt_t<<<dim3(16, 16), 256, 0, stream>>>(W0, W0t, 1024, 1024);
  cvt_t<<<dim3(4, 64), 256, 0, stream>>>(P, Ptb, 4096, 256);
  k_qkv<<<dim3(12, 64), 512, 0, stream>>>(Xh, Wqt, qt, kvt);
  k_proj<<<dim3(2, 64, 2), 256, 0, stream>>>(Ptb, kvt, kpv);
  k_attn<<<dim3(64, 64), 256, 0, stream>>>(qt, kpv, aout);
  k_out<<<dim3(8, 128), 256, 0, stream>>>(aout, W0t, Out);
}

// Round 8
// 445.203 us; speedup vs baseline: 1.4802x; 1.0076x over previous
//
#include <hip/hip_runtime.h>
#include <stdint.h>
#include <stddef.h>

#define TB    4096
#define NDIM  1024
#define NH    16
#define KPROJ 256
#define DH    64
#define NBH   64

typedef _Float16 f16;
typedef _Float16 f16x8 __attribute__((ext_vector_type(8)));
typedef float    f32x4 __attribute__((ext_vector_type(4)));

__device__ __forceinline__ void glds16(const f16* g, f16* l) {
  __builtin_amdgcn_global_load_lds((const __attribute__((address_space(1))) void*)g,
                                   (__attribute__((address_space(3))) void*)l, 16, 0, 0);
}

// ---------------------------------------------------------------------------
// fp32 -> fp16 elementwise (X)
// ---------------------------------------------------------------------------
__launch_bounds__(256)
__global__ void cvt_x(const float* __restrict__ in, f16* __restrict__ out) {
  size_t i = ((size_t)blockIdx.x * 256 + threadIdx.x) * 8;
  float4 v0 = *(const float4*)(in + i);
  float4 v1 = *(const float4*)(in + i + 4);
  union { f16 h[8]; uint4 u; } pk;
  pk.h[0] = (f16)v0.x; pk.h[1] = (f16)v0.y; pk.h[2] = (f16)v0.z; pk.h[3] = (f16)v0.w;
  pk.h[4] = (f16)v1.x; pk.h[5] = (f16)v1.y; pk.h[6] = (f16)v1.z; pk.h[7] = (f16)v1.w;
  *(uint4*)(out + i) = pk.u;
}

// ---------------------------------------------------------------------------
// fp32 [R][C] -> fp16 transposed [C][R]
// ---------------------------------------------------------------------------
__launch_bounds__(256)
__global__ void cvt_t(const float* __restrict__ in, f16* __restrict__ out, int R, int C) {
  __shared__ __align__(16) f16 s[64][72];
  const int tid = threadIdx.x;
  const int c0 = blockIdx.x * 64, r0 = blockIdx.y * 64;
#pragma unroll
  for (int it = 0; it < 4; ++it) {
    int chunk = it * 256 + tid;
    int r_l = chunk >> 4, c4 = (chunk & 15) * 4;
    float4 v = *(const float4*)(in + (size_t)(r0 + r_l) * C + c0 + c4);
    s[c4 + 0][r_l] = (f16)v.x; s[c4 + 1][r_l] = (f16)v.y;
    s[c4 + 2][r_l] = (f16)v.z; s[c4 + 3][r_l] = (f16)v.w;
  }
  __syncthreads();
#pragma unroll
  for (int it = 0; it < 2; ++it) {
    int chunk = it * 256 + tid;
    int c_l = chunk >> 3, rc = (chunk & 7) * 8;
    *(uint4*)(out + (size_t)(c0 + c_l) * R + r0 + rc) = *(const uint4*)&s[c_l][rc];
  }
}

// ---------------------------------------------------------------------------
// Stage 1: qkv = Xh @ Wt^T  (M=16384, N=3072, K=1024), 8-phase 256x256x64
// schedule. 512 thr / 8 waves, wave output = 128 rows x 64 cols (2M x 4N,
// acc[8][4]) — 24 ds_read_b128 per 64 MFMA (vs 36 for the 256x32 shape,
// which was LDS-read-bound at 31% MfmaUtil). B-frags (8 reads) register-
// cached once per K-tile; A-frags 4 reads/phase. LDS = 4 A-half-slots +
// 4 B-half-slots (128x64 f16, 128 KB), both-sides XOR-16B swizzle.
// Half-tile stream order per tile: B0,B1,A0,A1; one half staged per phase;
// vmcnt(6) at tile boundaries (3 halves in flight), vmcnt(0) only before
// the last tile. Raw s_barrier (no vmcnt drain).
// Epilogue: einops split f = 48d+16r+h, store q/k/v TRANSPOSED [bh][d][t].
// ---------------------------------------------------------------------------
__launch_bounds__(512, 2)
__global__ void k_qkv(const f16* __restrict__ Xh, const f16* __restrict__ Wt,
                      f16* __restrict__ qt, f16* __restrict__ kvt) {
  __shared__ __align__(16) f16 sA[4][128 * 64];  // 64 KB, A half-slots
  __shared__ __align__(16) f16 sB[4][128 * 64];  // 64 KB, B half-slots
  const int tid = threadIdx.x;
  const int w = tid >> 6, lane = tid & 63;
  const int quad = lane >> 4, l15 = lane & 15;
  const int bn0 = blockIdx.x * 256, bm0 = blockIdx.y * 256;
  const int wm = (w >> 2) * 128, wn = (w & 3) * 64;

  // staging geometry: per 64-row round, thread covers row w*8+(lane>>3),
  // 16B-group (lane&7); inverse swizzle on the GLOBAL column group.
  const int srow = w * 8 + (lane >> 3);
  const int scolg = ((lane & 7) ^ (lane >> 3)) * 8;
  const f16* Ag = Xh + (size_t)(bm0 + srow) * NDIM + scolg;
  const f16* Bg = Wt + (size_t)(bn0 + srow) * NDIM + scolg;

  auto stage = [&](int H) {  // H = 4*tile + {0:B0,1:B1,2:A0,3:A1}
    int h2 = H & 3, th = H >> 2;
    int k0 = th * 64;
    if (h2 < 2) {
      f16* slot = sB[(th & 1) * 2 + h2];
      const f16* g = Bg + (size_t)(h2 * 128) * NDIM + k0;
      glds16(g, slot + w * 512);
      glds16(g + (size_t)64 * NDIM, slot + 4096 + w * 512);
    } else {
      int h = h2 - 2;
      f16* slot = sA[(th & 1) * 2 + h];
      const f16* g = Ag + (size_t)(h * 128) * NDIM + k0;
      glds16(g, slot + w * 512);
      glds16(g + (size_t)64 * NDIM, slot + 4096 + w * 512);
    }
  };

  f32x4 acc[8][4];
#pragma unroll
  for (int i = 0; i < 8; ++i)
#pragma unroll
    for (int j = 0; j < 4; ++j) acc[i][j] = (f32x4){0.f, 0.f, 0.f, 0.f};

  // prologue: tile0 (4 halves) + tile1's B0,B1,A0 -> keep 3 halves in flight
  for (int H = 0; H < 7; ++H) stage(H);
  asm volatile("s_waitcnt vmcnt(6)" ::: "memory");
  __builtin_amdgcn_s_barrier();
  asm volatile("" ::: "memory");

  const int x0 = (quad ^ (l15 & 7)) * 8;  // swizzled f16 offset, ks=0
  const int x1 = x0 ^ 32;                 // ks=1: group^4 <=> f16off^32

  for (int t = 0; t < 16; ++t) {
    const f16* aS = sA[(t & 1) * 2 + (w >> 2)];          // this wave's 128 M-rows
    const f16* bS = sB[(t & 1) * 2 + ((w & 3) >> 1)];    // this wave's N-half

    // B-frags for the whole K-tile (read once, kept in regs: 8 ds_read)
    f16x8 bf[4][2];
#pragma unroll
    for (int j = 0; j < 4; ++j) {
      const f16* r = bS + (((w & 3) & 1) * 64 + j * 16 + l15) * 64;
      bf[j][0] = *(const f16x8*)(r + x0);
      bf[j][1] = *(const f16x8*)(r + x1);
    }

#pragma unroll
    for (int q = 0; q < 4; ++q) {
      f16x8 af[2][2];
#pragma unroll
      for (int i2 = 0; i2 < 2; ++i2) {
        const f16* r = aS + ((q * 2 + i2) * 16 + l15) * 64;
        af[i2][0] = *(const f16x8*)(r + x0);
        af[i2][1] = *(const f16x8*)(r + x1);
      }
      int H = 4 * t + q + 7;
      if (H < 64) stage(H);
      asm volatile("" ::: "memory");
      __builtin_amdgcn_s_barrier();
      __builtin_amdgcn_s_setprio(1);
#pragma unroll
      for (int i2 = 0; i2 < 2; ++i2)
#pragma unroll
        for (int j = 0; j < 4; ++j) {
          acc[q * 2 + i2][j] =
              __builtin_amdgcn_mfma_f32_16x16x32_f16(af[i2][0], bf[j][0], acc[q * 2 + i2][j], 0, 0, 0);
          acc[q * 2 + i2][j] =
              __builtin_amdgcn_mfma_f32_16x16x32_f16(af[i2][1], bf[j][1], acc[q * 2 + i2][j], 0, 0, 0);
        }
      __builtin_amdgcn_s_setprio(0);
      asm volatile("" ::: "memory");
      __builtin_amdgcn_s_barrier();
    }

    if (t < 15) {  // tile boundary: next tile fully resident; 3 halves in flight
      if (t == 14) asm volatile("s_waitcnt vmcnt(0)" ::: "memory");
      else         asm volatile("s_waitcnt vmcnt(6)" ::: "memory");
      __builtin_amdgcn_s_barrier();
      asm volatile("" ::: "memory");
    }
  }

  // epilogue: einops scatter, 8B stores (4 t-consecutive rows packed)
#pragma unroll
  for (int i = 0; i < 8; ++i) {
    int mrow = bm0 + wm + i * 16 + quad * 4;
    int bb = mrow >> 12, tt = mrow & 4095;
#pragma unroll
    for (int j = 0; j < 4; ++j) {
      int f = bn0 + wn + j * 16 + l15;
      int d = f / 48;
      int rem = f - d * 48;
      int rr = rem >> 4, h = rem & 15;
      f16* base = (rr == 0) ? qt : kvt + (size_t)(rr - 1) * ((size_t)NBH * DH * TB);
      size_t off = ((size_t)((bb * NH + h) * DH + d)) * TB + tt;
      union { f16 hh[4]; uint2 u; } pk;
#pragma unroll
      for (int r = 0; r < 4; ++r) pk.hh[r] = (f16)acc[i][j][r];
      *(uint2*)(base + off) = pk.u;
    }
  }
}

// ---------------------------------------------------------------------------
// Stage 2: kp/vp = Pt @ kvt^T per (bh, r): M=128(kappa), N=64(d), K=4096(t).
// rv==0 (k): store kp [bh][kappa][d]   (contiguous d for S B-frags)
// rv==1 (v): store vpT [bh][d][kappa]  (contiguous kappa for PV B-frags)
// ---------------------------------------------------------------------------
__launch_bounds__(256)
__global__ void k_proj(const f16* __restrict__ Pt, const f16* __restrict__ kvt,
                       f16* __restrict__ kpv) {
  __shared__ __align__(16) f16 As[128 * 32];
  __shared__ __align__(16) f16 Bs[64 * 32];
  const int tid = threadIdx.x;
  const int w = tid >> 6, lane = tid & 63;
  const int quad = lane >> 4, l15 = lane & 15;
  const int km0 = blockIdx.x * 128;
  const int bh = blockIdx.y, rv = blockIdx.z;
  const int srow = lane >> 2, skc = lane & 3;
  const f16* Bbase = kvt + (size_t)(rv * NBH + bh) * DH * TB;  // [d][t]

  f32x4 acc[2][4];
#pragma unroll
  for (int i = 0; i < 2; ++i)
#pragma unroll
    for (int j = 0; j < 4; ++j) acc[i][j] = (f32x4){0.f, 0.f, 0.f, 0.f};

  const f16* Ag0 = Pt + (size_t)(km0 + w * 32 + srow) * TB + skc * 8;
  const f16* Bg0 = Bbase + (size_t)(w * 16 + srow) * TB + skc * 8;
  f16* Al0 = As + (w * 32) * 32;
  f16* Bl0 = Bs + (w * 16) * 32;

  for (int k0 = 0; k0 < TB; k0 += 32) {
    glds16(Ag0 + k0, Al0);
    glds16(Ag0 + (size_t)16 * TB + k0, Al0 + 16 * 32);
    glds16(Bg0 + k0, Bl0);
    __syncthreads();
    f16x8 a[2], b[4];
#pragma unroll
    for (int i = 0; i < 2; ++i) a[i] = *(const f16x8*)(As + (w * 32 + i * 16 + l15) * 32 + quad * 8);
#pragma unroll
    for (int j = 0; j < 4; ++j) b[j] = *(const f16x8*)(Bs + (j * 16 + l15) * 32 + quad * 8);
#pragma unroll
    for (int i = 0; i < 2; ++i)
#pragma unroll
      for (int j = 0; j < 4; ++j)
        acc[i][j] = __builtin_amdgcn_mfma_f32_16x16x32_f16(a[i], b[j], acc[i][j], 0, 0, 0);
    __syncthreads();
  }

  if (rv == 0) {
#pragma unroll
    for (int i = 0; i < 2; ++i) {
      int kap0 = km0 + w * 32 + i * 16 + quad * 4;
#pragma unroll
      for (int j = 0; j < 4; ++j) {
        int d = j * 16 + l15;
#pragma unroll
        for (int r = 0; r < 4; ++r)
          kpv[((size_t)bh * KPROJ + kap0 + r) * DH + d] = (f16)acc[i][j][r];
      }
    }
  } else {
    f16* vpT = kpv + (size_t)NBH * KPROJ * DH;
#pragma unroll
    for (int i = 0; i < 2; ++i) {
      int kap0 = km0 + w * 32 + i * 16 + quad * 4;
#pragma unroll
      for (int j = 0; j < 4; ++j) {
        int d = j * 16 + l15;
        union { f16 hh[4]; uint2 u; } pk;
#pragma unroll
        for (int r = 0; r < 4; ++r) pk.hh[r] = (f16)acc[i][j][r];
        *(uint2*)&vpT[((size_t)bh * DH + d) * KPROJ + kap0] = pk.u;
      }
    }
  }
}

// ---------------------------------------------------------------------------
// Stage 3+4: fused MFMA attention (passing round-6/7 version). kp/vpT staged
// through one shared 32KB LDS region via async glds16 with both-sides XOR
// swizzle; S fully unrolled (sc[16] in VGPRs); vpT stage latency hidden
// under softmax; output staged via Ps -> 16B coalesced stores.
// ---------------------------------------------------------------------------
__launch_bounds__(256)
__global__ void k_attn(const f16* __restrict__ qt, const f16* __restrict__ kpv,
                       f16* __restrict__ aout) {
  __shared__ __align__(16) f16 Ps[4][16][264];  // 33 KB; first 8KB doubles as Qs
  __shared__ __align__(16) f16 Ks[16384];       // 32 KB; kp, then vpT
  f16* Qs = &Ps[0][0][0];
  const int tid = threadIdx.x;
  const int w = tid >> 6, lane = tid & 63;
  const int quad = lane >> 4, l15 = lane & 15;
  const int bh = blockIdx.y;
  const int tb = blockIdx.x * 64;
  const int b = bh >> 4, h = bh & 15;

  const f16* kpb = kpv + (size_t)bh * (KPROJ * DH);
  const f16* vpb = kpv + (size_t)NBH * KPROJ * DH + (size_t)bh * (DH * KPROJ);

  // stage Qs [64d][64t] (linear) + kp [256][64] swizzled (col16 ^= row&7)
  {
    const f16* qg = qt + (size_t)bh * DH * TB + tb;
#pragma unroll
    for (int c = 0; c < 2; ++c) {
      int d0 = w * 16 + c * 8;
      glds16(qg + (size_t)(d0 + (lane >> 3)) * TB + (lane & 7) * 8, Qs + d0 * 64);
    }
    const int kcolg = ((lane & 7) ^ (lane >> 3)) * 8;
    const int krow0 = w * 64 + (lane >> 3);
#pragma unroll
    for (int it = 0; it < 8; ++it)
      glds16(kpb + (size_t)(krow0 + it * 8) * DH + kcolg, Ks + w * 4096 + it * 512);
  }
  __syncthreads();

  // q A-frags: A[m=l15 (t)][k=quad*8+j (d)], one-time scalar LDS reads
  f16x8 aq[2];
#pragma unroll
  for (int ks = 0; ks < 2; ++ks)
#pragma unroll
    for (int j = 0; j < 8; ++j)
      aq[ks][j] = Qs[(ks * 32 + quad * 8 + j) * 64 + w * 16 + l15];

  // S: 16 n-tiles; B-frags from swizzled kp in LDS. Fully unrolled.
  f32x4 sc[16];
  const int sc0 = (quad ^ (l15 & 7)) * 8;
#pragma unroll
  for (int nt = 0; nt < 16; ++nt) {
    const f16* krow = Ks + (nt * 16 + l15) * 64;
    f16x8 b0 = *(const f16x8*)(krow + sc0);
    f16x8 b1 = *(const f16x8*)(krow + (sc0 ^ 32));
    f32x4 c = (f32x4){0.f, 0.f, 0.f, 0.f};
    c = __builtin_amdgcn_mfma_f32_16x16x32_f16(aq[0], b0, c, 0, 0, 0);
    c = __builtin_amdgcn_mfma_f32_16x16x32_f16(aq[1], b1, c, 0, 0, 0);
    sc[nt] = c;
  }

  // softmax; rows live at (quad*4+r), cols nt*16+l15
  float mx[4] = {-1e30f, -1e30f, -1e30f, -1e30f};
#pragma unroll
  for (int nt = 0; nt < 16; ++nt)
#pragma unroll
    for (int r = 0; r < 4; ++r) {
      float s = sc[nt][r] * 0.125f;
      sc[nt][r] = s;
      mx[r] = fmaxf(mx[r], s);
    }
#pragma unroll
  for (int r = 0; r < 4; ++r)
#pragma unroll
    for (int off = 1; off < 16; off <<= 1) mx[r] = fmaxf(mx[r], __shfl_xor(mx[r], off));

  __syncthreads();  // all waves done reading kp + Qs

  // issue vpT stage NOW (async); latency hides under exp/sum + P-pack below
  {
#pragma unroll
    for (int it = 0; it < 8; ++it) {
      int r = w * 16 + it * 2 + (lane >> 5);
      int colg = ((lane & 31) ^ (r & 7)) * 8;
      glds16(vpb + (size_t)r * KPROJ + colg, Ks + w * 4096 + it * 512);
    }
  }

  float sm[4] = {0.f, 0.f, 0.f, 0.f};
#pragma unroll
  for (int nt = 0; nt < 16; ++nt)
#pragma unroll
    for (int r = 0; r < 4; ++r) {
      float e = __expf(sc[nt][r] - mx[r]);
      sc[nt][r] = e;
      sm[r] += e;
    }
#pragma unroll
  for (int r = 0; r < 4; ++r)
#pragma unroll
    for (int off = 1; off < 16; off <<= 1) sm[r] += __shfl_xor(sm[r], off);

  // P -> LDS (pack lane pairs -> b32 writes, even l15 lanes only)
#pragma unroll
  for (int nt = 0; nt < 16; ++nt)
#pragma unroll
    for (int r = 0; r < 4; ++r) {
      f16 hh = (f16)sc[nt][r];
      uint32_t hb = (uint32_t)__builtin_bit_cast(uint16_t, hh);
      uint32_t nb = (uint32_t)__shfl_xor((int)hb, 1);
      if (!(lane & 1))
        *(uint32_t*)&Ps[w][quad * 4 + r][nt * 16 + l15] = (hb & 0xffffu) | (nb << 16);
    }

  __syncthreads();  // vpT staged + P visible

  // PV: M=16 t, N=64 d, K=256 kappa; A from Ps[w], B from swizzled vpT in LDS
  f32x4 oc[4];
#pragma unroll
  for (int j = 0; j < 4; ++j) oc[j] = (f32x4){0.f, 0.f, 0.f, 0.f};
#pragma unroll
  for (int kk = 0; kk < 8; ++kk) {
    f16x8 pa = *(const f16x8*)&Ps[w][l15][kk * 32 + quad * 8];
#pragma unroll
    for (int nd = 0; nd < 4; ++nd) {
      int row = nd * 16 + l15;
      int c = ((kk * 4 + quad) ^ (l15 & 7)) * 8;
      f16x8 bv = *(const f16x8*)(Ks + row * KPROJ + c);
      oc[nd] = __builtin_amdgcn_mfma_f32_16x16x32_f16(pa, bv, oc[nd], 0, 0, 0);
    }
  }

  // epilogue: divide by row sum, stage tile in Ps[w], 16B coalesced stores
#pragma unroll
  for (int nd = 0; nd < 4; ++nd)
#pragma unroll
    for (int r = 0; r < 4; ++r)
      Ps[w][quad * 4 + r][nd * 16 + l15] = (f16)(oc[nd][r] / sm[r]);

  const int orow = lane >> 3, oc8 = (lane & 7) * 8;
  const size_t obase = ((size_t)b * TB + tb + w * 16) * NDIM + h * 64 + oc8;
#pragma unroll
  for (int g = 0; g < 2; ++g)
    *(f16x8*)(aout + obase + (size_t)(g * 8 + orow) * NDIM) =
        *(const f16x8*)&Ps[w][g * 8 + orow][oc8];
}

// ---------------------------------------------------------------------------
// Stage 5: Out = aout @ W0t^T  (M=16384, N=1024, K=1024) fp16 MFMA, fp32 out.
// ---------------------------------------------------------------------------
__launch_bounds__(256)
__global__ void k_out(const f16* __restrict__ A, const f16* __restrict__ Bt,
                      float* __restrict__ Out) {
  __shared__ __align__(16) f16 As[128 * 32];
  __shared__ __align__(16) f16 Bs[128 * 32];
  const int tid = threadIdx.x;
  const int w = tid >> 6, lane = tid & 63;
  const int quad = lane >> 4, l15 = lane & 15;
  const int bn0 = blockIdx.x * 128, bm0 = blockIdx.y * 128;
  const int wm = (w & 1) * 64, wn = (w >> 1) * 64;
  const int srow = lane >> 2, skc = lane & 3;

  f32x4 acc[4][4];
#pragma unroll
  for (int i = 0; i < 4; ++i)
#pragma unroll
    for (int j = 0; j < 4; ++j) acc[i][j] = (f32x4){0.f, 0.f, 0.f, 0.f};

  const f16* Ag0 = A + (size_t)(bm0 + w * 32 + srow) * NDIM + skc * 8;
  const f16* Bg0 = Bt + (size_t)(bn0 + w * 32 + srow) * NDIM + skc * 8;
  f16* Al0 = As + (w * 32) * 32;
  f16* Bl0 = Bs + (w * 32) * 32;

  for (int k0 = 0; k0 < NDIM; k0 += 32) {
    glds16(Ag0 + k0, Al0);
    glds16(Ag0 + (size_t)16 * NDIM + k0, Al0 + 16 * 32);
    glds16(Bg0 + k0, Bl0);
    glds16(Bg0 + (size_t)16 * NDIM + k0, Bl0 + 16 * 32);
    __syncthreads();
    f16x8 a[4], b[4];
#pragma unroll
    for (int i = 0; i < 4; ++i) a[i] = *(const f16x8*)(As + (wm + i * 16 + l15) * 32 + quad * 8);
#pragma unroll
    for (int j = 0; j < 4; ++j) b[j] = *(const f16x8*)(Bs + (wn + j * 16 + l15) * 32 + quad * 8);
#pragma unroll
    for (int i = 0; i < 4; ++i)
#pragma unroll
      for (int j = 0; j < 4; ++j)
        acc[i][j] = __builtin_amdgcn_mfma_f32_16x16x32_f16(a[i], b[j], acc[i][j], 0, 0, 0);
    __syncthreads();
  }

#pragma unroll
  for (int i = 0; i < 4; ++i) {
    int m = bm0 + wm + i * 16 + quad * 4;
#pragma unroll
    for (int j = 0; j < 4; ++j) {
      int n = bn0 + wn + j * 16 + l15;
#pragma unroll
      for (int r = 0; r < 4; ++r) Out[(size_t)(m + r) * NDIM + n] = acc[i][j][r];
    }
  }
}

// ---------------------------------------------------------------------------
extern "C" void kernel_launch(void* const* d_in, const int* in_sizes, int n_in,
                              void* d_out, int out_size, void* d_ws, size_t ws_size,
                              hipStream_t stream) {
  const float* X    = (const float*)d_in[0];  // [4,4096,1024]
  const float* P    = (const float*)d_in[1];  // [4096,256]
  const float* Wqkv = (const float*)d_in[2];  // [1024,3072]
  const float* W0   = (const float*)d_in[3];  // [1024,1024]
  float* Out = (float*)d_out;

  char* ws = (char*)d_ws;
  const size_t MB = 1ull << 20;
  f16* Xh   = (f16*)(ws);             // 32 MB (reused as aout after k_qkv)
  f16* aout = (f16*)(ws);
  f16* qt   = (f16*)(ws + 32 * MB);   // 32 MB  [bh][d][t]
  f16* kvt  = (f16*)(ws + 64 * MB);   // 64 MB  [r][bh][d][t]
  f16* kpv  = (f16*)(ws + 128 * MB);  // 4 MB   kp [bh][kap][d] + vpT [bh][d][kap]
  f16* Wqt  = (f16*)(ws + 132 * MB);  // 6 MB   [3072][1024]
  f16* W0t  = (f16*)(ws + 138 * MB);  // 2 MB   [1024][1024]
  f16* Ptb  = (f16*)(ws + 140 * MB);  // 2 MB   [256][4096]

  cvt_x<<<dim3(8192), 256, 0, stream>>>(X, Xh);
  cvt_t<<<dim3(48, 16), 256, 0, stream>>>(Wqkv, Wqt, 1024, 3072);
  cvt_t<<<dim3(16, 16), 256, 0, stream>>>(W0, W0t, 1024, 1024);
  cvt_t<<<dim3(4, 64), 256, 0, stream>>>(P, Ptb, 4096, 256);
  k_qkv<<<dim3(12, 64), 512, 0, stream>>>(Xh, Wqt, qt, kvt);
  k_proj<<<dim3(2, 64, 2), 256, 0, stream>>>(Ptb, kvt, kpv);
  k_attn<<<dim3(64, 64), 256, 0, stream>>>(qt, kpv, aout);
  k_out<<<dim3(8, 128), 256, 0, stream>>>(aout, W0t, Out);
}

// Round 11
// 416.453 us; speedup vs baseline: 1.5824x; 1.0690x over previous
//
#include <hip/hip_runtime.h>
#include <stdint.h>
#include <stddef.h>

#define TB    4096
#define NDIM  1024
#define NH    16
#define KPROJ 256
#define DH    64
#define NBH   64

typedef _Float16 f16;
typedef _Float16 f16x8 __attribute__((ext_vector_type(8)));
typedef float    f32x4 __attribute__((ext_vector_type(4)));

__device__ __forceinline__ void glds16(const f16* g, f16* l) {
  __builtin_amdgcn_global_load_lds((const __attribute__((address_space(1))) void*)g,
                                   (__attribute__((address_space(3))) void*)l, 16, 0, 0);
}

// ---------------------------------------------------------------------------
// fp32 -> fp16 elementwise (X)
// ---------------------------------------------------------------------------
__launch_bounds__(256)
__global__ void cvt_x(const float* __restrict__ in, f16* __restrict__ out) {
  size_t i = ((size_t)blockIdx.x * 256 + threadIdx.x) * 8;
  float4 v0 = *(const float4*)(in + i);
  float4 v1 = *(const float4*)(in + i + 4);
  union { f16 h[8]; uint4 u; } pk;
  pk.h[0] = (f16)v0.x; pk.h[1] = (f16)v0.y; pk.h[2] = (f16)v0.z; pk.h[3] = (f16)v0.w;
  pk.h[4] = (f16)v1.x; pk.h[5] = (f16)v1.y; pk.h[6] = (f16)v1.z; pk.h[7] = (f16)v1.w;
  *(uint4*)(out + i) = pk.u;
}

// ---------------------------------------------------------------------------
// fp32 [R][C] -> fp16 transposed [C][R]
// ---------------------------------------------------------------------------
__launch_bounds__(256)
__global__ void cvt_t(const float* __restrict__ in, f16* __restrict__ out, int R, int C) {
  __shared__ __align__(16) f16 s[64][72];
  const int tid = threadIdx.x;
  const int c0 = blockIdx.x * 64, r0 = blockIdx.y * 64;
#pragma unroll
  for (int it = 0; it < 4; ++it) {
    int chunk = it * 256 + tid;
    int r_l = chunk >> 4, c4 = (chunk & 15) * 4;
    float4 v = *(const float4*)(in + (size_t)(r0 + r_l) * C + c0 + c4);
    s[c4 + 0][r_l] = (f16)v.x; s[c4 + 1][r_l] = (f16)v.y;
    s[c4 + 2][r_l] = (f16)v.z; s[c4 + 3][r_l] = (f16)v.w;
  }
  __syncthreads();
#pragma unroll
  for (int it = 0; it < 2; ++it) {
    int chunk = it * 256 + tid;
    int c_l = chunk >> 3, rc = (chunk & 7) * 8;
    *(uint4*)(out + (size_t)(c0 + c_l) * R + r0 + rc) = *(const uint4*)&s[c_l][rc];
  }
}

// ---------------------------------------------------------------------------
// Stage 1: q = Xh @ Wq^T only (M=16384, N=1024, K=1024), 128x128x32 2-barrier
// template (k_out structure, 4+ passing runs). k/v never materialized:
// kp = P^T(XWk) = (P^T X)Wk via k_xp + k_kv. B rows gathered per-lane from
// interleaved Wqkv^T: f(n) = 48*(n&63) + (n>>6) (q slice, n = h*64+d).
// Epilogue: store q TRANSPOSED qt [bh][d][t] (uint2, 4 t-consecutive rows).
// ---------------------------------------------------------------------------
__launch_bounds__(256)
__global__ void k_q(const f16* __restrict__ Xh, const f16* __restrict__ Wt,
                    f16* __restrict__ qt) {
  __shared__ __align__(16) f16 As[128 * 32];
  __shared__ __align__(16) f16 Bs[128 * 32];
  const int tid = threadIdx.x;
  const int w = tid >> 6, lane = tid & 63;
  const int quad = lane >> 4, l15 = lane & 15;
  const int bn0 = blockIdx.x * 128, bm0 = blockIdx.y * 128;
  const int wm = (w & 1) * 64, wn = (w >> 1) * 64;
  const int srow = lane >> 2, skc = lane & 3;

  f32x4 acc[4][4];
#pragma unroll
  for (int i = 0; i < 4; ++i)
#pragma unroll
    for (int j = 0; j < 4; ++j) acc[i][j] = (f32x4){0.f, 0.f, 0.f, 0.f};

  const f16* Ag0 = Xh + (size_t)(bm0 + w * 32 + srow) * NDIM + skc * 8;
  const int n0 = bn0 + w * 32 + srow, n1 = n0 + 16;
  const f16* Bg0 = Wt + (size_t)(48 * (n0 & 63) + (n0 >> 6)) * NDIM + skc * 8;
  const f16* Bg1 = Wt + (size_t)(48 * (n1 & 63) + (n1 >> 6)) * NDIM + skc * 8;
  f16* Al0 = As + (w * 32) * 32;
  f16* Bl0 = Bs + (w * 32) * 32;

  for (int k0 = 0; k0 < NDIM; k0 += 32) {
    glds16(Ag0 + k0, Al0);
    glds16(Ag0 + (size_t)16 * NDIM + k0, Al0 + 16 * 32);
    glds16(Bg0 + k0, Bl0);
    glds16(Bg1 + k0, Bl0 + 16 * 32);
    __syncthreads();
    f16x8 a[4], bfr[4];
#pragma unroll
    for (int i = 0; i < 4; ++i) a[i] = *(const f16x8*)(As + (wm + i * 16 + l15) * 32 + quad * 8);
#pragma unroll
    for (int j = 0; j < 4; ++j) bfr[j] = *(const f16x8*)(Bs + (wn + j * 16 + l15) * 32 + quad * 8);
#pragma unroll
    for (int i = 0; i < 4; ++i)
#pragma unroll
      for (int j = 0; j < 4; ++j)
        acc[i][j] = __builtin_amdgcn_mfma_f32_16x16x32_f16(a[i], bfr[j], acc[i][j], 0, 0, 0);
    __syncthreads();
  }

  // epilogue: qt [bh][d][t], 8B stores (4 t-consecutive rows packed)
#pragma unroll
  for (int i = 0; i < 4; ++i) {
    int mrow = bm0 + wm + i * 16 + quad * 4;
    int bb = mrow >> 12, tt = mrow & 4095;
#pragma unroll
    for (int j = 0; j < 4; ++j) {
      int n = bn0 + wn + j * 16 + l15;
      int h = n >> 6, d = n & 63;
      size_t off = ((size_t)((bb * NH + h) * DH + d)) * TB + tt;
      union { f16 hh[4]; uint2 u; } pk;
#pragma unroll
      for (int r = 0; r < 4; ++r) pk.hh[r] = (f16)acc[i][j][r];
      *(uint2*)(qt + off) = pk.u;
    }
  }
}

// ---------------------------------------------------------------------------
// Stage 2a: Xp[b][kappa][c] = sum_t Ptb[kappa][t] * XhT[b][c][t]
// (M=128 kappa-tile, N=64 c-tile, K=4096). k_proj structure reused.
// ---------------------------------------------------------------------------
__launch_bounds__(256)
__global__ void k_xp(const f16* __restrict__ Pt, const f16* __restrict__ XhT,
                     f16* __restrict__ Xp) {
  __shared__ __align__(16) f16 As[128 * 32];
  __shared__ __align__(16) f16 Bs[64 * 32];
  const int tid = threadIdx.x;
  const int w = tid >> 6, lane = tid & 63;
  const int quad = lane >> 4, l15 = lane & 15;
  const int km0 = blockIdx.x * 128;
  const int c0 = blockIdx.y * 64, b = blockIdx.z;
  const int srow = lane >> 2, skc = lane & 3;
  const f16* Bbase = XhT + ((size_t)b * NDIM + c0) * TB;  // [c][t]

  f32x4 acc[2][4];
#pragma unroll
  for (int i = 0; i < 2; ++i)
#pragma unroll
    for (int j = 0; j < 4; ++j) acc[i][j] = (f32x4){0.f, 0.f, 0.f, 0.f};

  const f16* Ag0 = Pt + (size_t)(km0 + w * 32 + srow) * TB + skc * 8;
  const f16* Bg0 = Bbase + (size_t)(w * 16 + srow) * TB + skc * 8;
  f16* Al0 = As + (w * 32) * 32;
  f16* Bl0 = Bs + (w * 16) * 32;

  for (int k0 = 0; k0 < TB; k0 += 32) {
    glds16(Ag0 + k0, Al0);
    glds16(Ag0 + (size_t)16 * TB + k0, Al0 + 16 * 32);
    glds16(Bg0 + k0, Bl0);
    __syncthreads();
    f16x8 a[2], bfr[4];
#pragma unroll
    for (int i = 0; i < 2; ++i) a[i] = *(const f16x8*)(As + (w * 32 + i * 16 + l15) * 32 + quad * 8);
#pragma unroll
    for (int j = 0; j < 4; ++j) bfr[j] = *(const f16x8*)(Bs + (j * 16 + l15) * 32 + quad * 8);
#pragma unroll
    for (int i = 0; i < 2; ++i)
#pragma unroll
      for (int j = 0; j < 4; ++j)
        acc[i][j] = __builtin_amdgcn_mfma_f32_16x16x32_f16(a[i], bfr[j], acc[i][j], 0, 0, 0);
    __syncthreads();
  }

#pragma unroll
  for (int i = 0; i < 2; ++i) {
    int kap0 = km0 + w * 32 + i * 16 + quad * 4;
#pragma unroll
    for (int j = 0; j < 4; ++j) {
      int c = c0 + j * 16 + l15;
#pragma unroll
      for (int r = 0; r < 4; ++r)
        Xp[((size_t)b * KPROJ + kap0 + r) * NDIM + c] = (f16)acc[i][j][r];
    }
  }
}

// ---------------------------------------------------------------------------
// Stage 2b: kp/vpT = Xp @ W{k,v}^T  (M=1024 (b,kappa), N=1024 (h,d), K=1024).
// B rows gathered from Wqkv^T: f(n) = 48*(n&63) + 16*(1+rv) + (n>>6).
// k_out structure (128x128x32). Epilogue:
//   rv==0: kp [bh][kappa][d];  rv==1: vpT [bh][d][kappa] (uint2 packs).
// ---------------------------------------------------------------------------
__launch_bounds__(256)
__global__ void k_kv(const f16* __restrict__ Xp, const f16* __restrict__ Wt,
                     f16* __restrict__ kpv) {
  __shared__ __align__(16) f16 As[128 * 32];
  __shared__ __align__(16) f16 Bs[128 * 32];
  const int tid = threadIdx.x;
  const int w = tid >> 6, lane = tid & 63;
  const int quad = lane >> 4, l15 = lane & 15;
  const int bn0 = blockIdx.x * 128, bm0 = blockIdx.y * 128;
  const int rv = blockIdx.z;
  const int wm = (w & 1) * 64, wn = (w >> 1) * 64;
  const int srow = lane >> 2, skc = lane & 3;

  f32x4 acc[4][4];
#pragma unroll
  for (int i = 0; i < 4; ++i)
#pragma unroll
    for (int j = 0; j < 4; ++j) acc[i][j] = (f32x4){0.f, 0.f, 0.f, 0.f};

  const f16* Ag0 = Xp + (size_t)(bm0 + w * 32 + srow) * NDIM + skc * 8;
  const int n0 = bn0 + w * 32 + srow, n1 = n0 + 16;
  const f16* Bg0 = Wt + (size_t)(48 * (n0 & 63) + 16 * (1 + rv) + (n0 >> 6)) * NDIM + skc * 8;
  const f16* Bg1 = Wt + (size_t)(48 * (n1 & 63) + 16 * (1 + rv) + (n1 >> 6)) * NDIM + skc * 8;
  f16* Al0 = As + (w * 32) * 32;
  f16* Bl0 = Bs + (w * 32) * 32;

  for (int k0 = 0; k0 < NDIM; k0 += 32) {
    glds16(Ag0 + k0, Al0);
    glds16(Ag0 + (size_t)16 * NDIM + k0, Al0 + 16 * 32);
    glds16(Bg0 + k0, Bl0);
    glds16(Bg1 + k0, Bl0 + 16 * 32);
    __syncthreads();
    f16x8 a[4], bfr[4];
#pragma unroll
    for (int i = 0; i < 4; ++i) a[i] = *(const f16x8*)(As + (wm + i * 16 + l15) * 32 + quad * 8);
#pragma unroll
    for (int j = 0; j < 4; ++j) bfr[j] = *(const f16x8*)(Bs + (wn + j * 16 + l15) * 32 + quad * 8);
#pragma unroll
    for (int i = 0; i < 4; ++i)
#pragma unroll
      for (int j = 0; j < 4; ++j)
        acc[i][j] = __builtin_amdgcn_mfma_f32_16x16x32_f16(a[i], bfr[j], acc[i][j], 0, 0, 0);
    __syncthreads();
  }

  if (rv == 0) {
#pragma unroll
    for (int i = 0; i < 4; ++i) {
      int m = bm0 + wm + i * 16 + quad * 4;
      int b = m >> 8, kap = m & 255;
#pragma unroll
      for (int j = 0; j < 4; ++j) {
        int n = bn0 + wn + j * 16 + l15;
        int h = n >> 6, d = n & 63;
#pragma unroll
        for (int r = 0; r < 4; ++r)
          kpv[((size_t)(b * NH + h) * KPROJ + kap + r) * DH + d] = (f16)acc[i][j][r];
      }
    }
  } else {
    f16* vpT = kpv + (size_t)NBH * KPROJ * DH;
#pragma unroll
    for (int i = 0; i < 4; ++i) {
      int m = bm0 + wm + i * 16 + quad * 4;
      int b = m >> 8, kap = m & 255;
#pragma unroll
      for (int j = 0; j < 4; ++j) {
        int n = bn0 + wn + j * 16 + l15;
        int h = n >> 6, d = n & 63;
        union { f16 hh[4]; uint2 u; } pk;
#pragma unroll
        for (int r = 0; r < 4; ++r) pk.hh[r] = (f16)acc[i][j][r];
        *(uint2*)&vpT[((size_t)(b * NH + h) * DH + d) * KPROJ + kap] = pk.u;
      }
    }
  }
}

// ---------------------------------------------------------------------------
// Stage 3+4: fused MFMA attention (passing round-6/7/8 version, unchanged).
// ---------------------------------------------------------------------------
__launch_bounds__(256)
__global__ void k_attn(const f16* __restrict__ qt, const f16* __restrict__ kpv,
                       f16* __restrict__ aout) {
  __shared__ __align__(16) f16 Ps[4][16][264];  // 33 KB; first 8KB doubles as Qs
  __shared__ __align__(16) f16 Ks[16384];       // 32 KB; kp, then vpT
  f16* Qs = &Ps[0][0][0];
  const int tid = threadIdx.x;
  const int w = tid >> 6, lane = tid & 63;
  const int quad = lane >> 4, l15 = lane & 15;
  const int bh = blockIdx.y;
  const int tb = blockIdx.x * 64;
  const int b = bh >> 4, h = bh & 15;

  const f16* kpb = kpv + (size_t)bh * (KPROJ * DH);
  const f16* vpb = kpv + (size_t)NBH * KPROJ * DH + (size_t)bh * (DH * KPROJ);

  // stage Qs [64d][64t] (linear) + kp [256][64] swizzled (col16 ^= row&7)
  {
    const f16* qg = qt + (size_t)bh * DH * TB + tb;
#pragma unroll
    for (int c = 0; c < 2; ++c) {
      int d0 = w * 16 + c * 8;
      glds16(qg + (size_t)(d0 + (lane >> 3)) * TB + (lane & 7) * 8, Qs + d0 * 64);
    }
    const int kcolg = ((lane & 7) ^ (lane >> 3)) * 8;
    const int krow0 = w * 64 + (lane >> 3);
#pragma unroll
    for (int it = 0; it < 8; ++it)
      glds16(kpb + (size_t)(krow0 + it * 8) * DH + kcolg, Ks + w * 4096 + it * 512);
  }
  __syncthreads();

  // q A-frags: A[m=l15 (t)][k=quad*8+j (d)], one-time scalar LDS reads
  f16x8 aq[2];
#pragma unroll
  for (int ks = 0; ks < 2; ++ks)
#pragma unroll
    for (int j = 0; j < 8; ++j)
      aq[ks][j] = Qs[(ks * 32 + quad * 8 + j) * 64 + w * 16 + l15];

  // S: 16 n-tiles; B-frags from swizzled kp in LDS. Fully unrolled.
  f32x4 sc[16];
  const int sc0 = (quad ^ (l15 & 7)) * 8;
#pragma unroll
  for (int nt = 0; nt < 16; ++nt) {
    const f16* krow = Ks + (nt * 16 + l15) * 64;
    f16x8 b0 = *(const f16x8*)(krow + sc0);
    f16x8 b1 = *(const f16x8*)(krow + (sc0 ^ 32));
    f32x4 c = (f32x4){0.f, 0.f, 0.f, 0.f};
    c = __builtin_amdgcn_mfma_f32_16x16x32_f16(aq[0], b0, c, 0, 0, 0);
    c = __builtin_amdgcn_mfma_f32_16x16x32_f16(aq[1], b1, c, 0, 0, 0);
    sc[nt] = c;
  }

  // softmax; rows live at (quad*4+r), cols nt*16+l15
  float mx[4] = {-1e30f, -1e30f, -1e30f, -1e30f};
#pragma unroll
  for (int nt = 0; nt < 16; ++nt)
#pragma unroll
    for (int r = 0; r < 4; ++r) {
      float s = sc[nt][r] * 0.125f;
      sc[nt][r] = s;
      mx[r] = fmaxf(mx[r], s);
    }
#pragma unroll
  for (int r = 0; r < 4; ++r)
#pragma unroll
    for (int off = 1; off < 16; off <<= 1) mx[r] = fmaxf(mx[r], __shfl_xor(mx[r], off));

  __syncthreads();  // all waves done reading kp + Qs

  // issue vpT stage NOW (async); latency hides under exp/sum + P-pack below
  {
#pragma unroll
    for (int it = 0; it < 8; ++it) {
      int r = w * 16 + it * 2 + (lane >> 5);
      int colg = ((lane & 31) ^ (r & 7)) * 8;
      glds16(vpb + (size_t)r * KPROJ + colg, Ks + w * 4096 + it * 512);
    }
  }

  float sm[4] = {0.f, 0.f, 0.f, 0.f};
#pragma unroll
  for (int nt = 0; nt < 16; ++nt)
#pragma unroll
    for (int r = 0; r < 4; ++r) {
      float e = __expf(sc[nt][r] - mx[r]);
      sc[nt][r] = e;
      sm[r] += e;
    }
#pragma unroll
  for (int r = 0; r < 4; ++r)
#pragma unroll
    for (int off = 1; off < 16; off <<= 1) sm[r] += __shfl_xor(sm[r], off);

  // P -> LDS (pack lane pairs -> b32 writes, even l15 lanes only)
#pragma unroll
  for (int nt = 0; nt < 16; ++nt)
#pragma unroll
    for (int r = 0; r < 4; ++r) {
      f16 hh = (f16)sc[nt][r];
      uint32_t hb = (uint32_t)__builtin_bit_cast(uint16_t, hh);
      uint32_t nb = (uint32_t)__shfl_xor((int)hb, 1);
      if (!(lane & 1))
        *(uint32_t*)&Ps[w][quad * 4 + r][nt * 16 + l15] = (hb & 0xffffu) | (nb << 16);
    }

  __syncthreads();  // vpT staged + P visible

  // PV: M=16 t, N=64 d, K=256 kappa; A from Ps[w], B from swizzled vpT in LDS
  f32x4 oc[4];
#pragma unroll
  for (int j = 0; j < 4; ++j) oc[j] = (f32x4){0.f, 0.f, 0.f, 0.f};
#pragma unroll
  for (int kk = 0; kk < 8; ++kk) {
    f16x8 pa = *(const f16x8*)&Ps[w][l15][kk * 32 + quad * 8];
#pragma unroll
    for (int nd = 0; nd < 4; ++nd) {
      int row = nd * 16 + l15;
      int c = ((kk * 4 + quad) ^ (l15 & 7)) * 8;
      f16x8 bv = *(const f16x8*)(Ks + row * KPROJ + c);
      oc[nd] = __builtin_amdgcn_mfma_f32_16x16x32_f16(pa, bv, oc[nd], 0, 0, 0);
    }
  }

  // epilogue: divide by row sum, stage tile in Ps[w], 16B coalesced stores
#pragma unroll
  for (int nd = 0; nd < 4; ++nd)
#pragma unroll
    for (int r = 0; r < 4; ++r)
      Ps[w][quad * 4 + r][nd * 16 + l15] = (f16)(oc[nd][r] / sm[r]);

  const int orow = lane >> 3, oc8 = (lane & 7) * 8;
  const size_t obase = ((size_t)b * TB + tb + w * 16) * NDIM + h * 64 + oc8;
#pragma unroll
  for (int g = 0; g < 2; ++g)
    *(f16x8*)(aout + obase + (size_t)(g * 8 + orow) * NDIM) =
        *(const f16x8*)&Ps[w][g * 8 + orow][oc8];
}

// ---------------------------------------------------------------------------
// Stage 5: Out = aout @ W0t^T  (M=16384, N=1024, K=1024) fp16 MFMA, fp32 out.
// ---------------------------------------------------------------------------
__launch_bounds__(256)
__global__ void k_out(const f16* __restrict__ A, const f16* __restrict__ Bt,
                      float* __restrict__ Out) {
  __shared__ __align__(16) f16 As[128 * 32];
  __shared__ __align__(16) f16 Bs[128 * 32];
  const int tid = threadIdx.x;
  const int w = tid >> 6, lane = tid & 63;
  const int quad = lane >> 4, l15 = lane & 15;
  const int bn0 = blockIdx.x * 128, bm0 = blockIdx.y * 128;
  const int wm = (w & 1) * 64, wn = (w >> 1) * 64;
  const int srow = lane >> 2, skc = lane & 3;

  f32x4 acc[4][4];
#pragma unroll
  for (int i = 0; i < 4; ++i)
#pragma unroll
    for (int j = 0; j < 4; ++j) acc[i][j] = (f32x4){0.f, 0.f, 0.f, 0.f};

  const f16* Ag0 = A + (size_t)(bm0 + w * 32 + srow) * NDIM + skc * 8;
  const f16* Bg0 = Bt + (size_t)(bn0 + w * 32 + srow) * NDIM + skc * 8;
  f16* Al0 = As + (w * 32) * 32;
  f16* Bl0 = Bs + (w * 32) * 32;

  for (int k0 = 0; k0 < NDIM; k0 += 32) {
    glds16(Ag0 + k0, Al0);
    glds16(Ag0 + (size_t)16 * NDIM + k0, Al0 + 16 * 32);
    glds16(Bg0 + k0, Bl0);
    glds16(Bg0 + (size_t)16 * NDIM + k0, Bl0 + 16 * 32);
    __syncthreads();
    f16x8 a[4], b[4];
#pragma unroll
    for (int i = 0; i < 4; ++i) a[i] = *(const f16x8*)(As + (wm + i * 16 + l15) * 32 + quad * 8);
#pragma unroll
    for (int j = 0; j < 4; ++j) b[j] = *(const f16x8*)(Bs + (wn + j * 16 + l15) * 32 + quad * 8);
#pragma unroll
    for (int i = 0; i < 4; ++i)
#pragma unroll
      for (int j = 0; j < 4; ++j)
        acc[i][j] = __builtin_amdgcn_mfma_f32_16x16x32_f16(a[i], b[j], acc[i][j], 0, 0, 0);
    __syncthreads();
  }

#pragma unroll
  for (int i = 0; i < 4; ++i) {
    int m = bm0 + wm + i * 16 + quad * 4;
#pragma unroll
    for (int j = 0; j < 4; ++j) {
      int n = bn0 + wn + j * 16 + l15;
#pragma unroll
      for (int r = 0; r < 4; ++r) Out[(size_t)(m + r) * NDIM + n] = acc[i][j][r];
    }
  }
}

// ---------------------------------------------------------------------------
extern "C" void kernel_launch(void* const* d_in, const int* in_sizes, int n_in,
                              void* d_out, int out_size, void* d_ws, size_t ws_size,
                              hipStream_t stream) {
  const float* X    = (const float*)d_in[0];  // [4,4096,1024]
  const float* P    = (const float*)d_in[1];  // [4096,256]
  const float* Wqkv = (const float*)d_in[2];  // [1024,3072]
  const float* W0   = (const float*)d_in[3];  // [1024,1024]
  float* Out = (float*)d_out;

  char* ws = (char*)d_ws;
  const size_t MB = 1ull << 20;
  f16* Xh   = (f16*)(ws);             // 32 MB (reused as aout after k_q)
  f16* aout = (f16*)(ws);
  f16* qt   = (f16*)(ws + 32 * MB);   // 32 MB  [bh][d][t]
  f16* XhT  = (f16*)(ws + 64 * MB);   // 32 MB  [b][c][t]
  f16* Xp   = (f16*)(ws + 96 * MB);   // 2 MB   [b][kappa][c]
  f16* kpv  = (f16*)(ws + 128 * MB);  // 4 MB   kp [bh][kap][d] + vpT [bh][d][kap]
  f16* Wqt  = (f16*)(ws + 132 * MB);  // 6 MB   [3072][1024]
  f16* W0t  = (f16*)(ws + 138 * MB);  // 2 MB   [1024][1024]
  f16* Ptb  = (f16*)(ws + 140 * MB);  // 2 MB   [256][4096]

  cvt_x<<<dim3(8192), 256, 0, stream>>>(X, Xh);
  cvt_t<<<dim3(48, 16), 256, 0, stream>>>(Wqkv, Wqt, 1024, 3072);
  cvt_t<<<dim3(16, 16), 256, 0, stream>>>(W0, W0t, 1024, 1024);
  cvt_t<<<dim3(4, 64), 256, 0, stream>>>(P, Ptb, 4096, 256);
  for (int b = 0; b < 4; ++b)  // XhT[b] = transpose of X[b]
    cvt_t<<<dim3(16, 64), 256, 0, stream>>>(X + (size_t)b * 4194304,
                                            XhT + (size_t)b * 4194304, 4096, 1024);
  k_q<<<dim3(8, 128), 256, 0, stream>>>(Xh, Wqt, qt);
  k_xp<<<dim3(2, 16, 4), 256, 0, stream>>>(Ptb, XhT, Xp);
  k_kv<<<dim3(8, 8, 2), 256, 0, stream>>>(Xp, Wqt, kpv);
  k_attn<<<dim3(64, 64), 256, 0, stream>>>(qt, kpv, aout);
  k_out<<<dim3(8, 128), 256, 0, stream>>>(aout, W0t, Out);
}

// Round 12
// 404.217 us; speedup vs baseline: 1.6303x; 1.0303x over previous
//
#include <hip/hip_runtime.h>
#include <stdint.h>
#include <stddef.h>

#define TB    4096
#define NDIM  1024
#define NH    16
#define KPROJ 256
#define DH    64
#define NBH   64

typedef _Float16 f16;
typedef _Float16 f16x8 __attribute__((ext_vector_type(8)));
typedef float    f32x4 __attribute__((ext_vector_type(4)));

__device__ __forceinline__ void glds16(const f16* g, f16* l) {
  __builtin_amdgcn_global_load_lds((const __attribute__((address_space(1))) void*)g,
                                   (__attribute__((address_space(3))) void*)l, 16, 0, 0);
}

// ---------------------------------------------------------------------------
// fp32 [R][C] tile -> f16 SAME layout (out_lin) + f16 TRANSPOSED (out_t).
// Fuses the old cvt_x + cvt_t(XhT): X is read once instead of twice.
// ---------------------------------------------------------------------------
__launch_bounds__(256)
__global__ void cvt_xt(const float* __restrict__ in, f16* __restrict__ out_lin,
                       f16* __restrict__ out_t, int R, int C) {
  __shared__ __align__(16) f16 s[64][72];
  const int tid = threadIdx.x;
  const int c0 = blockIdx.x * 64, r0 = blockIdx.y * 64;
#pragma unroll
  for (int it = 0; it < 4; ++it) {
    int chunk = it * 256 + tid;
    int r_l = chunk >> 4, c4 = (chunk & 15) * 4;
    float4 v = *(const float4*)(in + (size_t)(r0 + r_l) * C + c0 + c4);
    union { f16 h[4]; uint2 u; } pk;
    pk.h[0] = (f16)v.x; pk.h[1] = (f16)v.y; pk.h[2] = (f16)v.z; pk.h[3] = (f16)v.w;
    *(uint2*)(out_lin + (size_t)(r0 + r_l) * C + c0 + c4) = pk.u;
    s[c4 + 0][r_l] = pk.h[0]; s[c4 + 1][r_l] = pk.h[1];
    s[c4 + 2][r_l] = pk.h[2]; s[c4 + 3][r_l] = pk.h[3];
  }
  __syncthreads();
#pragma unroll
  for (int it = 0; it < 2; ++it) {
    int chunk = it * 256 + tid;
    int c_l = chunk >> 3, rc = (chunk & 7) * 8;
    *(uint4*)(out_t + (size_t)(c0 + c_l) * R + r0 + rc) = *(const uint4*)&s[c_l][rc];
  }
}

// ---------------------------------------------------------------------------
// fp32 [R][C] -> fp16 transposed [C][R]
// ---------------------------------------------------------------------------
__launch_bounds__(256)
__global__ void cvt_t(const float* __restrict__ in, f16* __restrict__ out, int R, int C) {
  __shared__ __align__(16) f16 s[64][72];
  const int tid = threadIdx.x;
  const int c0 = blockIdx.x * 64, r0 = blockIdx.y * 64;
#pragma unroll
  for (int it = 0; it < 4; ++it) {
    int chunk = it * 256 + tid;
    int r_l = chunk >> 4, c4 = (chunk & 15) * 4;
    float4 v = *(const float4*)(in + (size_t)(r0 + r_l) * C + c0 + c4);
    s[c4 + 0][r_l] = (f16)v.x; s[c4 + 1][r_l] = (f16)v.y;
    s[c4 + 2][r_l] = (f16)v.z; s[c4 + 3][r_l] = (f16)v.w;
  }
  __syncthreads();
#pragma unroll
  for (int it = 0; it < 2; ++it) {
    int chunk = it * 256 + tid;
    int c_l = chunk >> 3, rc = (chunk & 7) * 8;
    *(uint4*)(out + (size_t)(c0 + c_l) * R + r0 + rc) = *(const uint4*)&s[c_l][rc];
  }
}

// ---------------------------------------------------------------------------
// Stage 1: q = Xh @ Wq^T only (M=16384, N=1024, K=1024), 128x128x32 2-barrier
// template. B rows gathered from interleaved Wqkv^T: f(n)=48*(n&63)+(n>>6).
// Epilogue: store q*0.125 (exact f16 exponent shift) TRANSPOSED qt [bh][d][t]
// — k_attn then skips the score scaling pass.
// ---------------------------------------------------------------------------
__launch_bounds__(256)
__global__ void k_q(const f16* __restrict__ Xh, const f16* __restrict__ Wt,
                    f16* __restrict__ qt) {
  __shared__ __align__(16) f16 As[128 * 32];
  __shared__ __align__(16) f16 Bs[128 * 32];
  const int tid = threadIdx.x;
  const int w = tid >> 6, lane = tid & 63;
  const int quad = lane >> 4, l15 = lane & 15;
  const int bn0 = blockIdx.x * 128, bm0 = blockIdx.y * 128;
  const int wm = (w & 1) * 64, wn = (w >> 1) * 64;
  const int srow = lane >> 2, skc = lane & 3;

  f32x4 acc[4][4];
#pragma unroll
  for (int i = 0; i < 4; ++i)
#pragma unroll
    for (int j = 0; j < 4; ++j) acc[i][j] = (f32x4){0.f, 0.f, 0.f, 0.f};

  const f16* Ag0 = Xh + (size_t)(bm0 + w * 32 + srow) * NDIM + skc * 8;
  const int n0 = bn0 + w * 32 + srow, n1 = n0 + 16;
  const f16* Bg0 = Wt + (size_t)(48 * (n0 & 63) + (n0 >> 6)) * NDIM + skc * 8;
  const f16* Bg1 = Wt + (size_t)(48 * (n1 & 63) + (n1 >> 6)) * NDIM + skc * 8;
  f16* Al0 = As + (w * 32) * 32;
  f16* Bl0 = Bs + (w * 32) * 32;

  for (int k0 = 0; k0 < NDIM; k0 += 32) {
    glds16(Ag0 + k0, Al0);
    glds16(Ag0 + (size_t)16 * NDIM + k0, Al0 + 16 * 32);
    glds16(Bg0 + k0, Bl0);
    glds16(Bg1 + k0, Bl0 + 16 * 32);
    __syncthreads();
    f16x8 a[4], bfr[4];
#pragma unroll
    for (int i = 0; i < 4; ++i) a[i] = *(const f16x8*)(As + (wm + i * 16 + l15) * 32 + quad * 8);
#pragma unroll
    for (int j = 0; j < 4; ++j) bfr[j] = *(const f16x8*)(Bs + (wn + j * 16 + l15) * 32 + quad * 8);
#pragma unroll
    for (int i = 0; i < 4; ++i)
#pragma unroll
      for (int j = 0; j < 4; ++j)
        acc[i][j] = __builtin_amdgcn_mfma_f32_16x16x32_f16(a[i], bfr[j], acc[i][j], 0, 0, 0);
    __syncthreads();
  }

  // epilogue: qt [bh][d][t], pre-scaled by 0.125, 8B stores
#pragma unroll
  for (int i = 0; i < 4; ++i) {
    int mrow = bm0 + wm + i * 16 + quad * 4;
    int bb = mrow >> 12, tt = mrow & 4095;
#pragma unroll
    for (int j = 0; j < 4; ++j) {
      int n = bn0 + wn + j * 16 + l15;
      int h = n >> 6, d = n & 63;
      size_t off = ((size_t)((bb * NH + h) * DH + d)) * TB + tt;
      union { f16 hh[4]; uint2 u; } pk;
#pragma unroll
      for (int r = 0; r < 4; ++r) pk.hh[r] = (f16)(acc[i][j][r] * 0.125f);
      *(uint2*)(qt + off) = pk.u;
    }
  }
}

// ---------------------------------------------------------------------------
// Stage 2a: Xp[b][kappa][c] = sum_t Ptb[kappa][t] * XhT[b][c][t]
// (M=128 kappa-tile, N=64 c-tile, K=4096). k_proj structure reused.
// ---------------------------------------------------------------------------
__launch_bounds__(256)
__global__ void k_xp(const f16* __restrict__ Pt, const f16* __restrict__ XhT,
                     f16* __restrict__ Xp) {
  __shared__ __align__(16) f16 As[128 * 32];
  __shared__ __align__(16) f16 Bs[64 * 32];
  const int tid = threadIdx.x;
  const int w = tid >> 6, lane = tid & 63;
  const int quad = lane >> 4, l15 = lane & 15;
  const int km0 = blockIdx.x * 128;
  const int c0 = blockIdx.y * 64, b = blockIdx.z;
  const int srow = lane >> 2, skc = lane & 3;
  const f16* Bbase = XhT + ((size_t)b * NDIM + c0) * TB;  // [c][t]

  f32x4 acc[2][4];
#pragma unroll
  for (int i = 0; i < 2; ++i)
#pragma unroll
    for (int j = 0; j < 4; ++j) acc[i][j] = (f32x4){0.f, 0.f, 0.f, 0.f};

  const f16* Ag0 = Pt + (size_t)(km0 + w * 32 + srow) * TB + skc * 8;
  const f16* Bg0 = Bbase + (size_t)(w * 16 + srow) * TB + skc * 8;
  f16* Al0 = As + (w * 32) * 32;
  f16* Bl0 = Bs + (w * 16) * 32;

  for (int k0 = 0; k0 < TB; k0 += 32) {
    glds16(Ag0 + k0, Al0);
    glds16(Ag0 + (size_t)16 * TB + k0, Al0 + 16 * 32);
    glds16(Bg0 + k0, Bl0);
    __syncthreads();
    f16x8 a[2], bfr[4];
#pragma unroll
    for (int i = 0; i < 2; ++i) a[i] = *(const f16x8*)(As + (w * 32 + i * 16 + l15) * 32 + quad * 8);
#pragma unroll
    for (int j = 0; j < 4; ++j) bfr[j] = *(const f16x8*)(Bs + (j * 16 + l15) * 32 + quad * 8);
#pragma unroll
    for (int i = 0; i < 2; ++i)
#pragma unroll
      for (int j = 0; j < 4; ++j)
        acc[i][j] = __builtin_amdgcn_mfma_f32_16x16x32_f16(a[i], bfr[j], acc[i][j], 0, 0, 0);
    __syncthreads();
  }

#pragma unroll
  for (int i = 0; i < 2; ++i) {
    int kap0 = km0 + w * 32 + i * 16 + quad * 4;
#pragma unroll
    for (int j = 0; j < 4; ++j) {
      int c = c0 + j * 16 + l15;
#pragma unroll
      for (int r = 0; r < 4; ++r)
        Xp[((size_t)b * KPROJ + kap0 + r) * NDIM + c] = (f16)acc[i][j][r];
    }
  }
}

// ---------------------------------------------------------------------------
// Stage 2b: kp/vpT = Xp @ W{k,v}^T  (M=1024 (b,kappa), N=1024 (h,d), K=1024).
// B rows gathered from Wqkv^T: f(n) = 48*(n&63) + 16*(1+rv) + (n>>6).
// ---------------------------------------------------------------------------
__launch_bounds__(256)
__global__ void k_kv(const f16* __restrict__ Xp, const f16* __restrict__ Wt,
                     f16* __restrict__ kpv) {
  __shared__ __align__(16) f16 As[128 * 32];
  __shared__ __align__(16) f16 Bs[128 * 32];
  const int tid = threadIdx.x;
  const int w = tid >> 6, lane = tid & 63;
  const int quad = lane >> 4, l15 = lane & 15;
  const int bn0 = blockIdx.x * 128, bm0 = blockIdx.y * 128;
  const int rv = blockIdx.z;
  const int wm = (w & 1) * 64, wn = (w >> 1) * 64;
  const int srow = lane >> 2, skc = lane & 3;

  f32x4 acc[4][4];
#pragma unroll
  for (int i = 0; i < 4; ++i)
#pragma unroll
    for (int j = 0; j < 4; ++j) acc[i][j] = (f32x4){0.f, 0.f, 0.f, 0.f};

  const f16* Ag0 = Xp + (size_t)(bm0 + w * 32 + srow) * NDIM + skc * 8;
  const int n0 = bn0 + w * 32 + srow, n1 = n0 + 16;
  const f16* Bg0 = Wt + (size_t)(48 * (n0 & 63) + 16 * (1 + rv) + (n0 >> 6)) * NDIM + skc * 8;
  const f16* Bg1 = Wt + (size_t)(48 * (n1 & 63) + 16 * (1 + rv) + (n1 >> 6)) * NDIM + skc * 8;
  f16* Al0 = As + (w * 32) * 32;
  f16* Bl0 = Bs + (w * 32) * 32;

  for (int k0 = 0; k0 < NDIM; k0 += 32) {
    glds16(Ag0 + k0, Al0);
    glds16(Ag0 + (size_t)16 * NDIM + k0, Al0 + 16 * 32);
    glds16(Bg0 + k0, Bl0);
    glds16(Bg1 + k0, Bl0 + 16 * 32);
    __syncthreads();
    f16x8 a[4], bfr[4];
#pragma unroll
    for (int i = 0; i < 4; ++i) a[i] = *(const f16x8*)(As + (wm + i * 16 + l15) * 32 + quad * 8);
#pragma unroll
    for (int j = 0; j < 4; ++j) bfr[j] = *(const f16x8*)(Bs + (wn + j * 16 + l15) * 32 + quad * 8);
#pragma unroll
    for (int i = 0; i < 4; ++i)
#pragma unroll
      for (int j = 0; j < 4; ++j)
        acc[i][j] = __builtin_amdgcn_mfma_f32_16x16x32_f16(a[i], bfr[j], acc[i][j], 0, 0, 0);
    __syncthreads();
  }

  if (rv == 0) {
#pragma unroll
    for (int i = 0; i < 4; ++i) {
      int m = bm0 + wm + i * 16 + quad * 4;
      int b = m >> 8, kap = m & 255;
#pragma unroll
      for (int j = 0; j < 4; ++j) {
        int n = bn0 + wn + j * 16 + l15;
        int h = n >> 6, d = n & 63;
#pragma unroll
        for (int r = 0; r < 4; ++r)
          kpv[((size_t)(b * NH + h) * KPROJ + kap + r) * DH + d] = (f16)acc[i][j][r];
      }
    }
  } else {
    f16* vpT = kpv + (size_t)NBH * KPROJ * DH;
#pragma unroll
    for (int i = 0; i < 4; ++i) {
      int m = bm0 + wm + i * 16 + quad * 4;
      int b = m >> 8, kap = m & 255;
#pragma unroll
      for (int j = 0; j < 4; ++j) {
        int n = bn0 + wn + j * 16 + l15;
        int h = n >> 6, d = n & 63;
        union { f16 hh[4]; uint2 u; } pk;
#pragma unroll
        for (int r = 0; r < 4; ++r) pk.hh[r] = (f16)acc[i][j][r];
        *(uint2*)&vpT[((size_t)(b * NH + h) * DH + d) * KPROJ + kap] = pk.u;
      }
    }
  }
}

// ---------------------------------------------------------------------------
// Stage 3+4: fused MFMA attention, 2-tile version. Block = 128 t-rows
// (grid 2048): Qs [64d][128t] (16KB, aliases Ps), kp staged once serves S for
// BOTH 64-row groups, vpT staged once serves both PV passes. Same 3-barrier
// structure as the passing round-8 kernel; Ps[w] reuse between groups is
// same-wave sequential (compiler-ordered LDS deps). q arrives pre-scaled.
// ---------------------------------------------------------------------------
__launch_bounds__(256, 2)
__global__ void k_attn(const f16* __restrict__ qt, const f16* __restrict__ kpv,
                       f16* __restrict__ aout) {
  __shared__ __align__(16) f16 Ps[4][16][264];  // 33 KB; first 16KB doubles as Qs
  __shared__ __align__(16) f16 Ks[16384];       // 32 KB; kp, then vpT
  f16* Qs = &Ps[0][0][0];
  const int tid = threadIdx.x;
  const int w = tid >> 6, lane = tid & 63;
  const int quad = lane >> 4, l15 = lane & 15;
  const int bh = blockIdx.y;
  const int tb = blockIdx.x * 128;
  const int b = bh >> 4, h = bh & 15;

  const f16* kpb = kpv + (size_t)bh * (KPROJ * DH);
  const f16* vpb = kpv + (size_t)NBH * KPROJ * DH + (size_t)bh * (DH * KPROJ);

  // stage Qs [64 d][128 t] (linear) + kp [256][64] swizzled (col16 ^= row&7)
  {
    const f16* qg = qt + (size_t)bh * DH * TB + tb;
#pragma unroll
    for (int c = 0; c < 4; ++c) {
      int d0 = w * 16 + c * 4;
      glds16(qg + (size_t)(d0 + (lane >> 4)) * TB + (lane & 15) * 8, Qs + d0 * 128);
    }
    const int kcolg = ((lane & 7) ^ (lane >> 3)) * 8;
    const int krow0 = w * 64 + (lane >> 3);
#pragma unroll
    for (int it = 0; it < 8; ++it)
      glds16(kpb + (size_t)(krow0 + it * 8) * DH + kcolg, Ks + w * 4096 + it * 512);
  }
  __syncthreads();

  // q A-frags for both groups (one-time scalar LDS reads; Qs dies after this)
  f16x8 aq[2][2];
#pragma unroll
  for (int g = 0; g < 2; ++g)
#pragma unroll
    for (int ks = 0; ks < 2; ++ks)
#pragma unroll
      for (int j = 0; j < 8; ++j)
        aq[g][ks][j] = Qs[(ks * 32 + quad * 8 + j) * 128 + g * 64 + w * 16 + l15];

  // S for both groups while kp is resident. Fully unrolled (reg residency).
  f32x4 sc[2][16];
  const int sc0 = (quad ^ (l15 & 7)) * 8;
#pragma unroll
  for (int g = 0; g < 2; ++g)
#pragma unroll
    for (int nt = 0; nt < 16; ++nt) {
      const f16* krow = Ks + (nt * 16 + l15) * 64;
      f16x8 b0 = *(const f16x8*)(krow + sc0);
      f16x8 b1 = *(const f16x8*)(krow + (sc0 ^ 32));
      f32x4 c = (f32x4){0.f, 0.f, 0.f, 0.f};
      c = __builtin_amdgcn_mfma_f32_16x16x32_f16(aq[g][0], b0, c, 0, 0, 0);
      c = __builtin_amdgcn_mfma_f32_16x16x32_f16(aq[g][1], b1, c, 0, 0, 0);
      sc[g][nt] = c;
    }

  // row max (q pre-scaled, no mul pass)
  float mx[2][4];
#pragma unroll
  for (int g = 0; g < 2; ++g)
#pragma unroll
    for (int r = 0; r < 4; ++r) mx[g][r] = -1e30f;
#pragma unroll
  for (int g = 0; g < 2; ++g)
#pragma unroll
    for (int nt = 0; nt < 16; ++nt)
#pragma unroll
      for (int r = 0; r < 4; ++r) mx[g][r] = fmaxf(mx[g][r], sc[g][nt][r]);
#pragma unroll
  for (int g = 0; g < 2; ++g)
#pragma unroll
    for (int r = 0; r < 4; ++r)
#pragma unroll
      for (int off = 1; off < 16; off <<= 1) mx[g][r] = fmaxf(mx[g][r], __shfl_xor(mx[g][r], off));

  __syncthreads();  // all waves done reading kp + Qs

  // issue vpT stage NOW (async); latency hides under exp/sum + P-pack below
  {
#pragma unroll
    for (int it = 0; it < 8; ++it) {
      int r = w * 16 + it * 2 + (lane >> 5);
      int colg = ((lane & 31) ^ (r & 7)) * 8;
      glds16(vpb + (size_t)r * KPROJ + colg, Ks + w * 4096 + it * 512);
    }
  }

  float sm[2][4] = {{0.f, 0.f, 0.f, 0.f}, {0.f, 0.f, 0.f, 0.f}};
#pragma unroll
  for (int g = 0; g < 2; ++g)
#pragma unroll
    for (int nt = 0; nt < 16; ++nt)
#pragma unroll
      for (int r = 0; r < 4; ++r) {
        float e = __expf(sc[g][nt][r] - mx[g][r]);
        sc[g][nt][r] = e;
        sm[g][r] += e;
      }
#pragma unroll
  for (int g = 0; g < 2; ++g)
#pragma unroll
    for (int r = 0; r < 4; ++r)
#pragma unroll
      for (int off = 1; off < 16; off <<= 1) sm[g][r] += __shfl_xor(sm[g][r], off);
  float rs[2][4];
#pragma unroll
  for (int g = 0; g < 2; ++g)
#pragma unroll
    for (int r = 0; r < 4; ++r) rs[g][r] = 1.0f / sm[g][r];

  // P(group 0) -> LDS (pack lane pairs -> b32 writes, even l15 lanes only)
#pragma unroll
  for (int nt = 0; nt < 16; ++nt)
#pragma unroll
    for (int r = 0; r < 4; ++r) {
      f16 hh = (f16)sc[0][nt][r];
      uint32_t hb = (uint32_t)__builtin_bit_cast(uint16_t, hh);
      uint32_t nb = (uint32_t)__shfl_xor((int)hb, 1);
      if (!(lane & 1))
        *(uint32_t*)&Ps[w][quad * 4 + r][nt * 16 + l15] = (hb & 0xffffu) | (nb << 16);
    }

  __syncthreads();  // vpT staged + P0 visible

  const int orow = lane >> 3, oc8 = (lane & 7) * 8;

#pragma unroll
  for (int g = 0; g < 2; ++g) {
    if (g == 1) {
      // P(group 1) -> Ps[w] (wave-private reuse; same-wave LDS ordering)
#pragma unroll
      for (int nt = 0; nt < 16; ++nt)
#pragma unroll
        for (int r = 0; r < 4; ++r) {
          f16 hh = (f16)sc[1][nt][r];
          uint32_t hb = (uint32_t)__builtin_bit_cast(uint16_t, hh);
          uint32_t nb = (uint32_t)__shfl_xor((int)hb, 1);
          if (!(lane & 1))
            *(uint32_t*)&Ps[w][quad * 4 + r][nt * 16 + l15] = (hb & 0xffffu) | (nb << 16);
        }
    }

    // PV: M=16 t, N=64 d, K=256 kappa; A from Ps[w], B from swizzled vpT
    f32x4 oc[4];
#pragma unroll
    for (int j = 0; j < 4; ++j) oc[j] = (f32x4){0.f, 0.f, 0.f, 0.f};
#pragma unroll
    for (int kk = 0; kk < 8; ++kk) {
      f16x8 pa = *(const f16x8*)&Ps[w][l15][kk * 32 + quad * 8];
#pragma unroll
      for (int nd = 0; nd < 4; ++nd) {
        int row = nd * 16 + l15;
        int c = ((kk * 4 + quad) ^ (l15 & 7)) * 8;
        f16x8 bv = *(const f16x8*)(Ks + row * KPROJ + c);
        oc[nd] = __builtin_amdgcn_mfma_f32_16x16x32_f16(pa, bv, oc[nd], 0, 0, 0);
      }
    }

    // epilogue: multiply by 1/rowsum, stage tile in Ps[w], 16B coalesced stores
#pragma unroll
    for (int nd = 0; nd < 4; ++nd)
#pragma unroll
      for (int r = 0; r < 4; ++r)
        Ps[w][quad * 4 + r][nd * 16 + l15] = (f16)(oc[nd][r] * rs[g][r]);

    const size_t obase = ((size_t)b * TB + tb + g * 64 + w * 16) * NDIM + h * 64 + oc8;
#pragma unroll
    for (int gg = 0; gg < 2; ++gg)
      *(f16x8*)(aout + obase + (size_t)(gg * 8 + orow) * NDIM) =
          *(const f16x8*)&Ps[w][gg * 8 + orow][oc8];
  }
}

// ---------------------------------------------------------------------------
// Stage 5: Out = aout @ W0t^T  (M=16384, N=1024, K=1024) fp16 MFMA, fp32 out.
// ---------------------------------------------------------------------------
__launch_bounds__(256)
__global__ void k_out(const f16* __restrict__ A, const f16* __restrict__ Bt,
                      float* __restrict__ Out) {
  __shared__ __align__(16) f16 As[128 * 32];
  __shared__ __align__(16) f16 Bs[128 * 32];
  const int tid = threadIdx.x;
  const int w = tid >> 6, lane = tid & 63;
  const int quad = lane >> 4, l15 = lane & 15;
  const int bn0 = blockIdx.x * 128, bm0 = blockIdx.y * 128;
  const int wm = (w & 1) * 64, wn = (w >> 1) * 64;
  const int srow = lane >> 2, skc = lane & 3;

  f32x4 acc[4][4];
#pragma unroll
  for (int i = 0; i < 4; ++i)
#pragma unroll
    for (int j = 0; j < 4; ++j) acc[i][j] = (f32x4){0.f, 0.f, 0.f, 0.f};

  const f16* Ag0 = A + (size_t)(bm0 + w * 32 + srow) * NDIM + skc * 8;
  const f16* Bg0 = Bt + (size_t)(bn0 + w * 32 + srow) * NDIM + skc * 8;
  f16* Al0 = As + (w * 32) * 32;
  f16* Bl0 = Bs + (w * 32) * 32;

  for (int k0 = 0; k0 < NDIM; k0 += 32) {
    glds16(Ag0 + k0, Al0);
    glds16(Ag0 + (size_t)16 * NDIM + k0, Al0 + 16 * 32);
    glds16(Bg0 + k0, Bl0);
    glds16(Bg0 + (size_t)16 * NDIM + k0, Bl0 + 16 * 32);
    __syncthreads();
    f16x8 a[4], b[4];
#pragma unroll
    for (int i = 0; i < 4; ++i) a[i] = *(const f16x8*)(As + (wm + i * 16 + l15) * 32 + quad * 8);
#pragma unroll
    for (int j = 0; j < 4; ++j) b[j] = *(const f16x8*)(Bs + (wn + j * 16 + l15) * 32 + quad * 8);
#pragma unroll
    for (int i = 0; i < 4; ++i)
#pragma unroll
      for (int j = 0; j < 4; ++j)
        acc[i][j] = __builtin_amdgcn_mfma_f32_16x16x32_f16(a[i], b[j], acc[i][j], 0, 0, 0);
    __syncthreads();
  }

#pragma unroll
  for (int i = 0; i < 4; ++i) {
    int m = bm0 + wm + i * 16 + quad * 4;
#pragma unroll
    for (int j = 0; j < 4; ++j) {
      int n = bn0 + wn + j * 16 + l15;
#pragma unroll
      for (int r = 0; r < 4; ++r) Out[(size_t)(m + r) * NDIM + n] = acc[i][j][r];
    }
  }
}

// ---------------------------------------------------------------------------
extern "C" void kernel_launch(void* const* d_in, const int* in_sizes, int n_in,
                              void* d_out, int out_size, void* d_ws, size_t ws_size,
                              hipStream_t stream) {
  const float* X    = (const float*)d_in[0];  // [4,4096,1024]
  const float* P    = (const float*)d_in[1];  // [4096,256]
  const float* Wqkv = (const float*)d_in[2];  // [1024,3072]
  const float* W0   = (const float*)d_in[3];  // [1024,1024]
  float* Out = (float*)d_out;

  char* ws = (char*)d_ws;
  const size_t MB = 1ull << 20;
  f16* Xh   = (f16*)(ws);             // 32 MB (reused as aout after k_q)
  f16* aout = (f16*)(ws);
  f16* qt   = (f16*)(ws + 32 * MB);   // 32 MB  [bh][d][t]
  f16* XhT  = (f16*)(ws + 64 * MB);   // 32 MB  [b][c][t]
  f16* Xp   = (f16*)(ws + 96 * MB);   // 2 MB   [b][kappa][c]
  f16* kpv  = (f16*)(ws + 128 * MB);  // 4 MB   kp [bh][kap][d] + vpT [bh][d][kap]
  f16* Wqt  = (f16*)(ws + 132 * MB);  // 6 MB   [3072][1024]
  f16* W0t  = (f16*)(ws + 138 * MB);  // 2 MB   [1024][1024]
  f16* Ptb  = (f16*)(ws + 140 * MB);  // 2 MB   [256][4096]

  for (int b = 0; b < 4; ++b)  // Xh (linear f16) + XhT (transposed) in one pass
    cvt_xt<<<dim3(16, 64), 256, 0, stream>>>(X + (size_t)b * 4194304,
                                             Xh + (size_t)b * 4194304,
                                             XhT + (size_t)b * 4194304, 4096, 1024);
  cvt_t<<<dim3(48, 16), 256, 0, stream>>>(Wqkv, Wqt, 1024, 3072);
  cvt_t<<<dim3(16, 16), 256, 0, stream>>>(W0, W0t, 1024, 1024);
  cvt_t<<<dim3(4, 64), 256, 0, stream>>>(P, Ptb, 4096, 256);
  k_q<<<dim3(8, 128), 256, 0, stream>>>(Xh, Wqt, qt);
  k_xp<<<dim3(2, 16, 4), 256, 0, stream>>>(Ptb, XhT, Xp);
  k_kv<<<dim3(8, 8, 2), 256, 0, stream>>>(Xp, Wqt, kpv);
  k_attn<<<dim3(32, 64), 256, 0, stream>>>(qt, kpv, aout);
  k_out<<<dim3(8, 128), 256, 0, stream>>>(aout, W0t, Out);
}